// Round 1
// baseline (450.142 us; speedup 1.0000x reference)
//
#include <hip/hip_runtime.h>
#include <stdint.h>

// ---------------- MLA decoder self-attention, bf16-MFMA pipeline ----------------
// S=4096 E=1024 H=16 HD=64 ROPE=32 NOPE=32 QR=512 KVR=512, causal.
// Stages: cast->bf16 | rope tables | GEMM(Wqa) | LN | GEMM(Wqb) | rope-pack q_full
//         GEMM(Wkva) | LN+rope k_pe | GEMM(Wkvb) | pack k_full,v | flash-attn | GEMM(Wo)

#define SLEN 4096
#define EDIM 1024
#define NH   16

typedef __attribute__((ext_vector_type(8))) short short8;
typedef __attribute__((ext_vector_type(4))) float f32x4;

__device__ __forceinline__ ushort f2bf(float f) {
  union { float f; uint32_t u; } v; v.f = f;
  return (ushort)((v.u + 0x7FFFu + ((v.u >> 16) & 1u)) >> 16);
}

#define GLD_LDS16(g, l) __builtin_amdgcn_global_load_lds(                      \
    (const __attribute__((address_space(1))) uint32_t*)(g),                    \
    (__attribute__((address_space(3))) uint32_t*)(l), 16, 0, 0)

// ---------------- elementwise: f32 -> bf16 cast (vectorized x4) ----------------
__global__ void cast_bf16(const float4* __restrict__ in, ushort* __restrict__ out, int n4) {
  int i = blockIdx.x * blockDim.x + threadIdx.x;
  if (i >= n4) return;
  float4 v = in[i];
  ushort4 o;
  o.x = f2bf(v.x); o.y = f2bf(v.y); o.z = f2bf(v.z); o.w = f2bf(v.w);
  *(ushort4*)(out + (size_t)i * 4) = o;
}

// ---------------- rope tables: cos/sin[s][16] ----------------
__global__ void rope_table(float* __restrict__ cosT, float* __restrict__ sinT) {
  int idx = blockIdx.x * blockDim.x + threadIdx.x;
  if (idx >= SLEN * 16) return;
  int s = idx >> 4, i = idx & 15;
  float inv = expf(-((float)(2 * i) / 32.0f) * logf(10000.0f));
  float ang = (float)s * inv;
  cosT[idx] = cosf(ang);
  sinT[idx] = sinf(ang);
}

// ---------------- GEMM: C[M,N] = A[M,K] * B[N,K]^T, bf16 in / f32 out ----------------
// 128x128 tile, BK=64, 4 waves (2x2), 16x16x32 bf16 MFMA, global_load_lds staging,
// XOR-swizzle (byte ^= (row&7)<<4) applied on SOURCE addr + READ addr (LDS dest linear).
__global__ __launch_bounds__(256, 2) void gemm_bt(
    const ushort* __restrict__ A, const ushort* __restrict__ B, float* __restrict__ C,
    int M, int N, int K) {
  __shared__ ushort As[128 * 64];
  __shared__ ushort Bs[128 * 64];
  const int tid = threadIdx.x;
  const int lane = tid & 63, wave = tid >> 6;
  const int bm = blockIdx.x * 128, bn = blockIdx.y * 128;
  const int wm = (wave >> 1) * 64, wn = (wave & 1) * 64;

  f32x4 acc[4][4];
#pragma unroll
  for (int m = 0; m < 4; ++m)
#pragma unroll
    for (int n = 0; n < 4; ++n) acc[m][n] = (f32x4)0.0f;

  const int srow0 = 32 * wave + (lane >> 3); // +8c
  const int scb = (lane & 7) << 4;           // byte col within 128B row

  for (int k0 = 0; k0 < K; k0 += 64) {
    __syncthreads();
#pragma unroll
    for (int c = 0; c < 4; ++c) {
      int r = srow0 + 8 * c;
      int srcb = scb ^ ((r & 7) << 4);
      const ushort* ga = A + (size_t)(bm + r) * K + k0 + (srcb >> 1);
      GLD_LDS16(ga, As + (32 * wave + 8 * c) * 64);
      int rb = bn + r; if (rb >= N) rb = N - 1;
      const ushort* gb = B + (size_t)rb * K + k0 + (srcb >> 1);
      GLD_LDS16(gb, Bs + (32 * wave + 8 * c) * 64);
    }
    __syncthreads();
#pragma unroll
    for (int kk = 0; kk < 2; ++kk) {
      short8 af[4], bf[4];
#pragma unroll
      for (int m = 0; m < 4; ++m) {
        int row = wm + m * 16 + (lane & 15);
        int cb = (kk * 64 + ((lane >> 4) << 4)) ^ ((row & 7) << 4);
        af[m] = *(const short8*)((const char*)As + row * 128 + cb);
      }
#pragma unroll
      for (int n = 0; n < 4; ++n) {
        int row = wn + n * 16 + (lane & 15);
        int cb = (kk * 64 + ((lane >> 4) << 4)) ^ ((row & 7) << 4);
        bf[n] = *(const short8*)((const char*)Bs + row * 128 + cb);
      }
#pragma unroll
      for (int m = 0; m < 4; ++m)
#pragma unroll
        for (int n = 0; n < 4; ++n)
          acc[m][n] = __builtin_amdgcn_mfma_f32_16x16x32_bf16(af[m], bf[n], acc[m][n], 0, 0, 0);
    }
  }
  // C/D layout: col = lane&15, row = (lane>>4)*4 + reg (m89-verified)
#pragma unroll
  for (int m = 0; m < 4; ++m) {
    int gm = bm + wm + m * 16 + ((lane >> 4) << 2);
#pragma unroll
    for (int n = 0; n < 4; ++n) {
      int gn = bn + wn + n * 16 + (lane & 15);
      if (gn < N) {
#pragma unroll
        for (int r = 0; r < 4; ++r) C[(size_t)(gm + r) * N + gn] = acc[m][n][r];
      }
    }
  }
}

// ---------------- LayerNorm over 512 cols (+optional k_pe rope), bf16 out ----------------
__global__ __launch_bounds__(256) void ln_kernel(
    const float* __restrict__ in, int ldin, const float* __restrict__ w,
    const float* __restrict__ b, ushort* __restrict__ out,
    const float* __restrict__ cosT, const float* __restrict__ sinT,
    ushort* __restrict__ kpe) {
  int row = blockIdx.x, tid = threadIdx.x;
  const float* px = in + (size_t)row * ldin;
  float x0 = px[tid], x1 = px[tid + 256];
  float s = x0 + x1, sq = x0 * x0 + x1 * x1;
#pragma unroll
  for (int off = 32; off; off >>= 1) {
    s += __shfl_down(s, off);
    sq += __shfl_down(sq, off);
  }
  __shared__ float redS[4], redQ[4];
  int wave = tid >> 6, lane = tid & 63;
  if (lane == 0) { redS[wave] = s; redQ[wave] = sq; }
  __syncthreads();
  float st = redS[0] + redS[1] + redS[2] + redS[3];
  float sqt = redQ[0] + redQ[1] + redQ[2] + redQ[3];
  float mean = st * (1.0f / 512.0f);
  float var = sqt * (1.0f / 512.0f) - mean * mean;
  float rstd = rsqrtf(var + 1e-5f);
  out[(size_t)row * 512 + tid] = f2bf((x0 - mean) * rstd * w[tid] + b[tid]);
  out[(size_t)row * 512 + tid + 256] = f2bf((x1 - mean) * rstd * w[tid + 256] + b[tid + 256]);
  if (kpe != nullptr && tid < 32) {
    int p = tid >> 1;
    float xa = px[512 + 2 * p], xb = px[512 + 2 * p + 1];
    float c = cosT[(row << 4) + p], sn = sinT[(row << 4) + p];
    float v = (tid & 1) ? (xa * sn + xb * c) : (xa * c - xb * sn);
    kpe[(row << 5) + tid] = f2bf(v);
  }
}

// ---------------- q_full: copy nope + rope(q_pe), bf16 [s][h*64+d] ----------------
__global__ void build_qfull(const float* __restrict__ q, const float* __restrict__ cosT,
                            const float* __restrict__ sinT, ushort* __restrict__ qf) {
  int idx = blockIdx.x * blockDim.x + threadIdx.x; // s*1024 + h*64 + d
  if (idx >= SLEN * EDIM) return;
  int d = idx & 63;
  int s = idx >> 10;
  const float* base = q + (size_t)(idx - d);
  float v;
  if (d < 32) {
    v = base[d];
  } else {
    int j = d - 32, p = j >> 1;
    float xa = base[32 + 2 * p], xb = base[33 + 2 * p];
    float c = cosT[(s << 4) + p], sn = sinT[(s << 4) + p];
    v = (j & 1) ? (xa * sn + xb * c) : (xa * c - xb * sn);
  }
  qf[idx] = f2bf(v);
}

// ---------------- pack k_full (nope + broadcast roped k_pe) and v ----------------
__global__ void pack_kv(const float* __restrict__ kvdec, const ushort* __restrict__ kpe,
                        ushort* __restrict__ kf, ushort* __restrict__ vf) {
  int idx = blockIdx.x * blockDim.x + threadIdx.x; // s*1024 + h*64 + d
  if (idx >= SLEN * EDIM) return;
  int d = idx & 63, h = (idx >> 6) & 15, s = idx >> 10;
  const float* base = kvdec + ((size_t)s * 16 + h) * 96;
  kf[idx] = (d < 32) ? f2bf(base[d]) : kpe[(s << 5) + d - 32];
  vf[idx] = f2bf(base[32 + d]);
}

// ---------------- flash attention: causal, 64 q-rows x 1 head per block ----------------
// 4 waves; each wave owns 16 q-rows. KVBLK=64. K staged via swizzled global_load_lds;
// V transposed into LDS ([hd][k], stride 72) at stage time; P via per-wave private LDS.
__global__ __launch_bounds__(256, 2) void flash_attn(
    const ushort* __restrict__ Qf, const ushort* __restrict__ Kf,
    const ushort* __restrict__ Vf, ushort* __restrict__ Of) {
  __shared__ ushort Klds[64 * 64];    // [64][64] bf16, XOR-swizzled storage
  __shared__ ushort Vt[64 * 72];      // [hd=64][k=64], pad->72 (conflict-free b128)
  __shared__ ushort Plds[4][16 * 72]; // per-wave [16 q][64 k], pad->72
  const int tid = threadIdx.x, lane = tid & 63, wave = tid >> 6;
  const int qb = blockIdx.x, h = blockIdx.y;
  const int q0 = qb * 64;

  // Q fragments for this wave's 16 rows (kept in regs for whole kernel)
  short8 aq[2];
  {
    const ushort* qrow =
        Qf + (((size_t)(q0 + wave * 16 + (lane & 15)) * 16 + h) << 6) + ((lane >> 4) << 3);
    aq[0] = *(const short8*)qrow;
    aq[1] = *(const short8*)(qrow + 32);
  }
  f32x4 oacc[4];
#pragma unroll
  for (int nf = 0; nf < 4; ++nf) oacc[nf] = (f32x4)0.0f;
  float mrun[4], lrun[4];
#pragma unroll
  for (int r = 0; r < 4; ++r) { mrun[r] = -1e30f; lrun[r] = 0.0f; }
  const float scale = 0.125f; // 1/sqrt(64)

  for (int kb = 0; kb <= qb; ++kb) {
    __syncthreads(); // previous tile fully consumed
    // ---- stage K (swizzled source -> linear LDS) ----
#pragma unroll
    for (int c = 0; c < 2; ++c) {
      int r = wave * 16 + c * 8 + (lane >> 3);
      int srcb = ((lane & 7) << 4) ^ ((r & 7) << 4);
      const ushort* gk = Kf + (((size_t)(kb * 64 + r) * 16 + h) << 6) + (srcb >> 1);
      GLD_LDS16(gk, Klds + (wave * 16 + c * 8) * 64);
    }
    // ---- stage V transposed: read [k][hd0..7] chunk, scatter to Vt[hd][k] ----
#pragma unroll
    for (int c = 0; c < 2; ++c) {
      int chunk = 256 * c + tid; // 512 chunks = 64 rows x 8
      int k = chunk >> 3, hd0 = (chunk & 7) << 3;
      const ushort* gv = Vf + (((size_t)(kb * 64 + k) * 16 + h) << 6) + hd0;
      short8 v8 = *(const short8*)gv;
#pragma unroll
      for (int j = 0; j < 8; ++j) Vt[(hd0 + j) * 72 + k] = (ushort)v8[j];
    }
    __syncthreads();

    // ---- S = Q K^T (this wave: 16 q x 64 k) ----
    f32x4 sfr[4];
#pragma unroll
    for (int n = 0; n < 4; ++n) sfr[n] = (f32x4)0.0f;
#pragma unroll
    for (int kk = 0; kk < 2; ++kk) {
#pragma unroll
      for (int n = 0; n < 4; ++n) {
        int row = n * 16 + (lane & 15);
        int cb = (kk * 64 + ((lane >> 4) << 4)) ^ ((row & 7) << 4);
        short8 bk = *(const short8*)((const char*)Klds + row * 128 + cb);
        sfr[n] = __builtin_amdgcn_mfma_f32_16x16x32_bf16(aq[kk], bk, sfr[n], 0, 0, 0);
      }
    }
    // ---- scale + causal mask (diagonal block only) + online softmax ----
    float pmax[4];
#pragma unroll
    for (int r = 0; r < 4; ++r) pmax[r] = -1e30f;
    const int qloc = wave * 16 + ((lane >> 4) << 2);
#pragma unroll
    for (int n = 0; n < 4; ++n) {
      int kloc = n * 16 + (lane & 15);
#pragma unroll
      for (int r = 0; r < 4; ++r) {
        float sv = sfr[n][r] * scale;
        if (kb == qb && kloc > qloc + r) sv = -1e30f;
        sfr[n][r] = sv;
        pmax[r] = fmaxf(pmax[r], sv);
      }
    }
#pragma unroll
    for (int r = 0; r < 4; ++r) {
#pragma unroll
      for (int off = 8; off >= 1; off >>= 1) pmax[r] = fmaxf(pmax[r], __shfl_xor(pmax[r], off));
    }
    float corr[4], psum[4];
#pragma unroll
    for (int r = 0; r < 4; ++r) {
      float mnew = fmaxf(mrun[r], pmax[r]);
      corr[r] = __expf(mrun[r] - mnew);
      mrun[r] = mnew;
      psum[r] = 0.0f;
    }
#pragma unroll
    for (int n = 0; n < 4; ++n) {
#pragma unroll
      for (int r = 0; r < 4; ++r) {
        float p = __expf(sfr[n][r] - mrun[r]);
        psum[r] += p;
        Plds[wave][(((lane >> 4) << 2) + r) * 72 + n * 16 + (lane & 15)] = f2bf(p);
      }
    }
#pragma unroll
    for (int r = 0; r < 4; ++r) {
#pragma unroll
      for (int off = 8; off >= 1; off >>= 1) psum[r] += __shfl_xor(psum[r], off);
      lrun[r] = lrun[r] * corr[r] + psum[r];
    }
#pragma unroll
    for (int nf = 0; nf < 4; ++nf) {
#pragma unroll
      for (int r = 0; r < 4; ++r) oacc[nf][r] *= corr[r];
    }
    // ---- O += P V  (A = P from private LDS, B = V^T tile) ----
    short8 ap[2];
#pragma unroll
    for (int kk = 0; kk < 2; ++kk)
      ap[kk] = *(const short8*)&Plds[wave][(lane & 15) * 72 + kk * 32 + ((lane >> 4) << 3)];
#pragma unroll
    for (int nf = 0; nf < 4; ++nf) {
#pragma unroll
      for (int kk = 0; kk < 2; ++kk) {
        short8 bv = *(const short8*)&Vt[(nf * 16 + (lane & 15)) * 72 + kk * 32 + ((lane >> 4) << 3)];
        oacc[nf] = __builtin_amdgcn_mfma_f32_16x16x32_bf16(ap[kk], bv, oacc[nf], 0, 0, 0);
      }
    }
  }
  // ---- epilogue: O /= l, write bf16 [s][h*64+d] ----
#pragma unroll
  for (int nf = 0; nf < 4; ++nf) {
#pragma unroll
    for (int r = 0; r < 4; ++r) {
      int gq = q0 + wave * 16 + ((lane >> 4) << 2) + r;
      int gd = h * 64 + nf * 16 + (lane & 15);
      Of[(size_t)gq * EDIM + gd] = f2bf(oacc[nf][r] / lrun[r]);
    }
  }
}

// ---------------- launcher ----------------
extern "C" void kernel_launch(void* const* d_in, const int* in_sizes, int n_in,
                              void* d_out, int out_size, void* d_ws, size_t ws_size,
                              hipStream_t stream) {
  const float* x     = (const float*)d_in[0];
  // d_in[1] = mask (causal tril) — structure known, not read
  const float* Wqa   = (const float*)d_in[2];
  const float* qa_w  = (const float*)d_in[3];
  const float* qa_b  = (const float*)d_in[4];
  const float* Wqb   = (const float*)d_in[5];
  const float* Wkva  = (const float*)d_in[6];
  const float* kva_w = (const float*)d_in[7];
  const float* kva_b = (const float*)d_in[8];
  const float* Wkvb  = (const float*)d_in[9];
  const float* Wo    = (const float*)d_in[10];
  float* out = (float*)d_out;

  char* ws = (char*)d_ws;
  size_t off = 0;
  auto alloc = [&](size_t bytes) {
    char* p = ws + off;
    off += (bytes + 255) & ~(size_t)255;
    return p;
  };
  ushort* xb     = (ushort*)alloc((size_t)SLEN * EDIM * 2);      // 8 MB
  ushort* wqa_b  = (ushort*)alloc((size_t)512 * 1024 * 2);
  ushort* wqb_b  = (ushort*)alloc((size_t)1024 * 512 * 2);
  ushort* wkva_b = (ushort*)alloc((size_t)544 * 1024 * 2);
  ushort* wkvb_b = (ushort*)alloc((size_t)1536 * 512 * 2);
  ushort* wo_b   = (ushort*)alloc((size_t)1024 * 1024 * 2);
  float*  cosT   = (float*)alloc((size_t)SLEN * 16 * 4);
  float*  sinT   = (float*)alloc((size_t)SLEN * 16 * 4);
  ushort* qc_b   = (ushort*)alloc((size_t)SLEN * 512 * 2);
  ushort* qf_b   = (ushort*)alloc((size_t)SLEN * EDIM * 2);
  float*  kv_f   = (float*)alloc((size_t)SLEN * 544 * 4);
  ushort* ckv_b  = (ushort*)alloc((size_t)SLEN * 512 * 2);
  ushort* kpe_b  = (ushort*)alloc((size_t)SLEN * 32 * 2);
  ushort* kf_b   = (ushort*)alloc((size_t)SLEN * EDIM * 2);
  ushort* vf_b   = (ushort*)alloc((size_t)SLEN * EDIM * 2);
  ushort* attn_b = (ushort*)alloc((size_t)SLEN * EDIM * 2);
  // aliased f32 region: qa (8.39MB) | q (16.78MB) then reused as kvdec (25.17MB)
  char* R = alloc((size_t)SLEN * 1536 * 4);
  float* qa_f    = (float*)R;
  float* q_f     = (float*)(R + (size_t)SLEN * 512 * 4);
  float* kvdec_f = (float*)R;

  auto cast = [&](const float* src, ushort* dst, int n) {
    cast_bf16<<<dim3((n / 4 + 255) / 256), 256, 0, stream>>>((const float4*)src, dst, n / 4);
  };
  cast(x, xb, SLEN * EDIM);
  cast(Wqa, wqa_b, 512 * 1024);
  cast(Wqb, wqb_b, 1024 * 512);
  cast(Wkva, wkva_b, 544 * 1024);
  cast(Wkvb, wkvb_b, 1536 * 512);
  cast(Wo, wo_b, 1024 * 1024);
  rope_table<<<dim3((SLEN * 16 + 255) / 256), 256, 0, stream>>>(cosT, sinT);

  // q path
  gemm_bt<<<dim3(32, 4), 256, 0, stream>>>(xb, wqa_b, qa_f, SLEN, 512, 1024);
  ln_kernel<<<dim3(SLEN), 256, 0, stream>>>(qa_f, 512, qa_w, qa_b, qc_b, nullptr, nullptr, nullptr);
  gemm_bt<<<dim3(32, 8), 256, 0, stream>>>(qc_b, wqb_b, q_f, SLEN, 1024, 512);
  build_qfull<<<dim3(SLEN * EDIM / 256), 256, 0, stream>>>(q_f, cosT, sinT, qf_b);

  // kv path
  gemm_bt<<<dim3(32, 5), 256, 0, stream>>>(xb, wkva_b, kv_f, SLEN, 544, 1024);
  ln_kernel<<<dim3(SLEN), 256, 0, stream>>>(kv_f, 544, kva_w, kva_b, ckv_b, cosT, sinT, kpe_b);
  gemm_bt<<<dim3(32, 12), 256, 0, stream>>>(ckv_b, wkvb_b, kvdec_f, SLEN, 1536, 512);
  pack_kv<<<dim3(SLEN * EDIM / 256), 256, 0, stream>>>(kvdec_f, kpe_b, kf_b, vf_b);

  // attention + output projection
  flash_attn<<<dim3(64, 16), 256, 0, stream>>>(qf_b, kf_b, vf_b, attn_b);
  gemm_bt<<<dim3(32, 8), 256, 0, stream>>>(attn_b, wo_b, out, SLEN, 1024, 1024);

  (void)in_sizes; (void)n_in; (void)out_size; (void)ws_size;
}

// Round 2
// 321.042 us; speedup vs baseline: 1.4021x; 1.4021x over previous
//
#include <hip/hip_runtime.h>
#include <stdint.h>

// ---------------- MLA decoder self-attention, bf16-MFMA pipeline ----------------
// S=4096 E=1024 H=16 HD=64 ROPE=32 NOPE=32 QR=512 KVR=512, causal.

#define SLEN 4096
#define EDIM 1024
#define NH   16

typedef __attribute__((ext_vector_type(8))) short short8;
typedef __attribute__((ext_vector_type(4))) float f32x4;

__device__ __forceinline__ ushort f2bf(float f) {
  union { float f; uint32_t u; } v; v.f = f;
  return (ushort)((v.u + 0x7FFFu + ((v.u >> 16) & 1u)) >> 16);
}

#define GLD_LDS16(g, l) __builtin_amdgcn_global_load_lds(                      \
    (const __attribute__((address_space(1))) uint32_t*)(g),                    \
    (__attribute__((address_space(3))) uint32_t*)(l), 16, 0, 0)

// ---------------- elementwise: f32 -> bf16 cast (vectorized x4) ----------------
__global__ void cast_bf16(const float4* __restrict__ in, ushort* __restrict__ out, int n4) {
  int i = blockIdx.x * blockDim.x + threadIdx.x;
  if (i >= n4) return;
  float4 v = in[i];
  ushort4 o;
  o.x = f2bf(v.x); o.y = f2bf(v.y); o.z = f2bf(v.z); o.w = f2bf(v.w);
  *(ushort4*)(out + (size_t)i * 4) = o;
}

// ---------------- rope tables: cos/sin[s][16] ----------------
__global__ void rope_table(float* __restrict__ cosT, float* __restrict__ sinT) {
  int idx = blockIdx.x * blockDim.x + threadIdx.x;
  if (idx >= SLEN * 16) return;
  int s = idx >> 4, i = idx & 15;
  float inv = expf(-((float)(2 * i) / 32.0f) * logf(10000.0f));
  float ang = (float)s * inv;
  cosT[idx] = cosf(ang);
  sinT[idx] = sinf(ang);
}

// ---------------- GEMM: C[M,N] = A[M,K] * B[N,K]^T, bf16 in / f32 out ----------------
__global__ __launch_bounds__(256, 2) void gemm_bt(
    const ushort* __restrict__ A, const ushort* __restrict__ B, float* __restrict__ C,
    int M, int N, int K) {
  __shared__ ushort As[128 * 64];
  __shared__ ushort Bs[128 * 64];
  const int tid = threadIdx.x;
  const int lane = tid & 63, wave = tid >> 6;
  const int bm = blockIdx.x * 128, bn = blockIdx.y * 128;
  const int wm = (wave >> 1) * 64, wn = (wave & 1) * 64;

  f32x4 acc[4][4];
#pragma unroll
  for (int m = 0; m < 4; ++m)
#pragma unroll
    for (int n = 0; n < 4; ++n) acc[m][n] = (f32x4)0.0f;

  const int srow0 = 32 * wave + (lane >> 3);
  const int scb = (lane & 7) << 4;

  for (int k0 = 0; k0 < K; k0 += 64) {
    __syncthreads();
#pragma unroll
    for (int c = 0; c < 4; ++c) {
      int r = srow0 + 8 * c;
      int srcb = scb ^ ((r & 7) << 4);
      const ushort* ga = A + (size_t)(bm + r) * K + k0 + (srcb >> 1);
      GLD_LDS16(ga, As + (32 * wave + 8 * c) * 64);
      int rb = bn + r; if (rb >= N) rb = N - 1;
      const ushort* gb = B + (size_t)rb * K + k0 + (srcb >> 1);
      GLD_LDS16(gb, Bs + (32 * wave + 8 * c) * 64);
    }
    __syncthreads();
#pragma unroll
    for (int kk = 0; kk < 2; ++kk) {
      short8 af[4], bf[4];
#pragma unroll
      for (int m = 0; m < 4; ++m) {
        int row = wm + m * 16 + (lane & 15);
        int cb = (kk * 64 + ((lane >> 4) << 4)) ^ ((row & 7) << 4);
        af[m] = *(const short8*)((const char*)As + row * 128 + cb);
      }
#pragma unroll
      for (int n = 0; n < 4; ++n) {
        int row = wn + n * 16 + (lane & 15);
        int cb = (kk * 64 + ((lane >> 4) << 4)) ^ ((row & 7) << 4);
        bf[n] = *(const short8*)((const char*)Bs + row * 128 + cb);
      }
#pragma unroll
      for (int m = 0; m < 4; ++m)
#pragma unroll
        for (int n = 0; n < 4; ++n)
          acc[m][n] = __builtin_amdgcn_mfma_f32_16x16x32_bf16(af[m], bf[n], acc[m][n], 0, 0, 0);
    }
  }
#pragma unroll
  for (int m = 0; m < 4; ++m) {
    int gm = bm + wm + m * 16 + ((lane >> 4) << 2);
#pragma unroll
    for (int n = 0; n < 4; ++n) {
      int gn = bn + wn + n * 16 + (lane & 15);
      if (gn < N) {
#pragma unroll
        for (int r = 0; r < 4; ++r) C[(size_t)(gm + r) * N + gn] = acc[m][n][r];
      }
    }
  }
}

// ---------------- LayerNorm over 512 cols (+optional k_pe rope), bf16 out ----------------
__global__ __launch_bounds__(256) void ln_kernel(
    const float* __restrict__ in, int ldin, const float* __restrict__ w,
    const float* __restrict__ b, ushort* __restrict__ out,
    const float* __restrict__ cosT, const float* __restrict__ sinT,
    ushort* __restrict__ kpe) {
  int row = blockIdx.x, tid = threadIdx.x;
  const float* px = in + (size_t)row * ldin;
  float x0 = px[tid], x1 = px[tid + 256];
  float s = x0 + x1, sq = x0 * x0 + x1 * x1;
#pragma unroll
  for (int off = 32; off; off >>= 1) {
    s += __shfl_down(s, off);
    sq += __shfl_down(sq, off);
  }
  __shared__ float redS[4], redQ[4];
  int wave = tid >> 6, lane = tid & 63;
  if (lane == 0) { redS[wave] = s; redQ[wave] = sq; }
  __syncthreads();
  float st = redS[0] + redS[1] + redS[2] + redS[3];
  float sqt = redQ[0] + redQ[1] + redQ[2] + redQ[3];
  float mean = st * (1.0f / 512.0f);
  float var = sqt * (1.0f / 512.0f) - mean * mean;
  float rstd = rsqrtf(var + 1e-5f);
  out[(size_t)row * 512 + tid] = f2bf((x0 - mean) * rstd * w[tid] + b[tid]);
  out[(size_t)row * 512 + tid + 256] = f2bf((x1 - mean) * rstd * w[tid + 256] + b[tid + 256]);
  if (kpe != nullptr && tid < 32) {
    int p = tid >> 1;
    float xa = px[512 + 2 * p], xb = px[512 + 2 * p + 1];
    float c = cosT[(row << 4) + p], sn = sinT[(row << 4) + p];
    float v = (tid & 1) ? (xa * sn + xb * c) : (xa * c - xb * sn);
    kpe[(row << 5) + tid] = f2bf(v);
  }
}

// ---------------- q_full: copy nope + rope(q_pe), bf16 [s][h*64+d] ----------------
__global__ void build_qfull(const float* __restrict__ q, const float* __restrict__ cosT,
                            const float* __restrict__ sinT, ushort* __restrict__ qf) {
  int idx = blockIdx.x * blockDim.x + threadIdx.x;
  if (idx >= SLEN * EDIM) return;
  int d = idx & 63;
  int s = idx >> 10;
  const float* base = q + (size_t)(idx - d);
  float v;
  if (d < 32) {
    v = base[d];
  } else {
    int j = d - 32, p = j >> 1;
    float xa = base[32 + 2 * p], xb = base[33 + 2 * p];
    float c = cosT[(s << 4) + p], sn = sinT[(s << 4) + p];
    v = (j & 1) ? (xa * sn + xb * c) : (xa * c - xb * sn);
  }
  qf[idx] = f2bf(v);
}

// ---------------- pack k_full + V^T (LDS-tiled transpose): vt[h][hd][s] ----------------
__global__ __launch_bounds__(256) void pack_kv2(
    const float* __restrict__ kvdec, const ushort* __restrict__ kpe,
    ushort* __restrict__ kf, ushort* __restrict__ vt) {
  __shared__ ushort T[64 * 65];  // [hd][s_loc], pad 65 -> ~2-way write, 2-way read
  const int tid = threadIdx.x;
  const int sb = blockIdx.x, h = blockIdx.y;
  const int s0 = sb * 64;
#pragma unroll 4
  for (int i = 0; i < 16; ++i) {
    int s_loc = i * 4 + (tid >> 6);
    int d = tid & 63;
    const float* base = kvdec + ((size_t)(s0 + s_loc) * 16 + h) * 96;
    T[d * 65 + s_loc] = f2bf(base[32 + d]);  // v
    ushort kval = (d < 32) ? f2bf(base[d]) : kpe[((s0 + s_loc) << 5) + (d - 32)];
    kf[(size_t)(s0 + s_loc) * EDIM + h * 64 + d] = kval;
  }
  __syncthreads();
#pragma unroll 4
  for (int i = 0; i < 16; ++i) {
    int hd = i * 4 + (tid >> 6);
    int s_off = tid & 63;
    vt[(size_t)(h * 64 + hd) * SLEN + s0 + s_off] = T[hd * 65 + s_off];
  }
}

// ---------------- flash attention: causal, 64 q-rows x 1 head per block ----------------
// 4 waves x 16 q-rows. KVBLK=64, K and V^T both staged via swizzled global_load_lds,
// double-buffered (2-phase): stage(t+1) issued before compute(t), 1 barrier/tile.
// Plds row-XOR swizzled (col ^= 8*((row>>2)&3)) -> conflict-free.
__global__ __launch_bounds__(256, 2) void flash_attn(
    const ushort* __restrict__ Qf, const ushort* __restrict__ Kf,
    const ushort* __restrict__ Vt, ushort* __restrict__ Of) {
  __shared__ ushort Klds[2][64 * 64];
  __shared__ ushort Vlds[2][64 * 64];
  __shared__ ushort Plds[4][16 * 72];
  const int tid = threadIdx.x, lane = tid & 63, wave = tid >> 6;
  const int qb = gridDim.x - 1 - blockIdx.x;  // long blocks dispatch first
  const int h = blockIdx.y;
  const int q0 = qb * 64;

  short8 aq[2];
  {
    const ushort* qrow =
        Qf + (((size_t)(q0 + wave * 16 + (lane & 15)) * 16 + h) << 6) + ((lane >> 4) << 3);
    aq[0] = *(const short8*)qrow;
    aq[1] = *(const short8*)(qrow + 32);
  }
  f32x4 oacc[4];
#pragma unroll
  for (int nf = 0; nf < 4; ++nf) oacc[nf] = (f32x4)0.0f;
  float mrun[4], lrun[4];
#pragma unroll
  for (int r = 0; r < 4; ++r) { mrun[r] = -1e30f; lrun[r] = 0.0f; }
  const float scale = 0.125f;

  const int strow = wave * 16 + (lane >> 3);       // staging row base (+0/+8)
  const int stscb = (lane & 7) << 4;               // staging byte col

  auto stage = [&](int kb, int buf) {
#pragma unroll
    for (int c = 0; c < 2; ++c) {
      int r = strow + c * 8;
      int srcb = stscb ^ ((r & 7) << 4);
      const ushort* gk = Kf + (((size_t)(kb * 64 + r) * 16 + h) << 6) + (srcb >> 1);
      GLD_LDS16(gk, &Klds[buf][(wave * 16 + c * 8) * 64]);
      const ushort* gv = Vt + (size_t)(h * 64 + r) * SLEN + kb * 64 + (srcb >> 1);
      GLD_LDS16(gv, &Vlds[buf][(wave * 16 + c * 8) * 64]);
    }
  };

  int cur = 0;
  stage(0, 0);
  __syncthreads();  // drains vmcnt

  for (int kb = 0; kb <= qb; ++kb) {
    if (kb < qb) stage(kb + 1, cur ^ 1);

    // ---- S = Q K^T (16 q x 64 k per wave) ----
    f32x4 sfr[4];
#pragma unroll
    for (int n = 0; n < 4; ++n) sfr[n] = (f32x4)0.0f;
#pragma unroll
    for (int kk = 0; kk < 2; ++kk) {
#pragma unroll
      for (int n = 0; n < 4; ++n) {
        int row = n * 16 + (lane & 15);
        int cb = (kk * 64 + ((lane >> 4) << 4)) ^ ((row & 7) << 4);
        short8 bk = *(const short8*)((const char*)&Klds[cur][0] + row * 128 + cb);
        sfr[n] = __builtin_amdgcn_mfma_f32_16x16x32_bf16(aq[kk], bk, sfr[n], 0, 0, 0);
      }
    }
    // ---- scale + causal mask + online softmax ----
    float pmax[4];
#pragma unroll
    for (int r = 0; r < 4; ++r) pmax[r] = -1e30f;
    const int qloc = wave * 16 + ((lane >> 4) << 2);
#pragma unroll
    for (int n = 0; n < 4; ++n) {
      int kloc = n * 16 + (lane & 15);
#pragma unroll
      for (int r = 0; r < 4; ++r) {
        float sv = sfr[n][r] * scale;
        if (kb == qb && kloc > qloc + r) sv = -1e30f;
        sfr[n][r] = sv;
        pmax[r] = fmaxf(pmax[r], sv);
      }
    }
#pragma unroll
    for (int r = 0; r < 4; ++r) {
#pragma unroll
      for (int off = 8; off >= 1; off >>= 1) pmax[r] = fmaxf(pmax[r], __shfl_xor(pmax[r], off));
    }
    float corr[4], psum[4];
#pragma unroll
    for (int r = 0; r < 4; ++r) {
      float mnew = fmaxf(mrun[r], pmax[r]);
      corr[r] = __expf(mrun[r] - mnew);
      mrun[r] = mnew;
      psum[r] = 0.0f;
    }
#pragma unroll
    for (int n = 0; n < 4; ++n) {
#pragma unroll
      for (int r = 0; r < 4; ++r) {
        float p = __expf(sfr[n][r] - mrun[r]);
        psum[r] += p;
        int prow = ((lane >> 4) << 2) + r;
        int pcol = (n * 16 + (lane & 15)) ^ (8 * ((prow >> 2) & 3));
        Plds[wave][prow * 72 + pcol] = f2bf(p);
      }
    }
#pragma unroll
    for (int r = 0; r < 4; ++r) {
#pragma unroll
      for (int off = 8; off >= 1; off >>= 1) psum[r] += __shfl_xor(psum[r], off);
      lrun[r] = lrun[r] * corr[r] + psum[r];
    }
#pragma unroll
    for (int nf = 0; nf < 4; ++nf) {
#pragma unroll
      for (int r = 0; r < 4; ++r) oacc[nf][r] *= corr[r];
    }
    // ---- O += P V ----
    short8 ap[2];
    {
      int rr = lane & 15;
#pragma unroll
      for (int kk = 0; kk < 2; ++kk) {
        int koff = (kk * 32 + ((lane >> 4) << 3)) ^ (8 * ((rr >> 2) & 3));
        ap[kk] = *(const short8*)&Plds[wave][rr * 72 + koff];
      }
    }
#pragma unroll
    for (int nf = 0; nf < 4; ++nf) {
#pragma unroll
      for (int kk = 0; kk < 2; ++kk) {
        int row = nf * 16 + (lane & 15);
        int cb = (kk * 64 + ((lane >> 4) << 4)) ^ ((row & 7) << 4);
        short8 bv = *(const short8*)((const char*)&Vlds[cur][0] + row * 128 + cb);
        oacc[nf] = __builtin_amdgcn_mfma_f32_16x16x32_bf16(ap[kk], bv, oacc[nf], 0, 0, 0);
      }
    }
    __syncthreads();  // all waves done with buf[cur]; stage(t+1) drained
    cur ^= 1;
  }
#pragma unroll
  for (int nf = 0; nf < 4; ++nf) {
#pragma unroll
    for (int r = 0; r < 4; ++r) {
      int gq = q0 + wave * 16 + ((lane >> 4) << 2) + r;
      int gd = h * 64 + nf * 16 + (lane & 15);
      Of[(size_t)gq * EDIM + gd] = f2bf(oacc[nf][r] / lrun[r]);
    }
  }
}

// ---------------- launcher ----------------
extern "C" void kernel_launch(void* const* d_in, const int* in_sizes, int n_in,
                              void* d_out, int out_size, void* d_ws, size_t ws_size,
                              hipStream_t stream) {
  const float* x     = (const float*)d_in[0];
  const float* Wqa   = (const float*)d_in[2];
  const float* qa_w  = (const float*)d_in[3];
  const float* qa_b  = (const float*)d_in[4];
  const float* Wqb   = (const float*)d_in[5];
  const float* Wkva  = (const float*)d_in[6];
  const float* kva_w = (const float*)d_in[7];
  const float* kva_b = (const float*)d_in[8];
  const float* Wkvb  = (const float*)d_in[9];
  const float* Wo    = (const float*)d_in[10];
  float* out = (float*)d_out;

  char* ws = (char*)d_ws;
  size_t off = 0;
  auto alloc = [&](size_t bytes) {
    char* p = ws + off;
    off += (bytes + 255) & ~(size_t)255;
    return p;
  };
  ushort* xb     = (ushort*)alloc((size_t)SLEN * EDIM * 2);
  ushort* wqa_b  = (ushort*)alloc((size_t)512 * 1024 * 2);
  ushort* wqb_b  = (ushort*)alloc((size_t)1024 * 512 * 2);
  ushort* wkva_b = (ushort*)alloc((size_t)544 * 1024 * 2);
  ushort* wkvb_b = (ushort*)alloc((size_t)1536 * 512 * 2);
  ushort* wo_b   = (ushort*)alloc((size_t)1024 * 1024 * 2);
  float*  cosT   = (float*)alloc((size_t)SLEN * 16 * 4);
  float*  sinT   = (float*)alloc((size_t)SLEN * 16 * 4);
  ushort* qc_b   = (ushort*)alloc((size_t)SLEN * 512 * 2);
  ushort* qf_b   = (ushort*)alloc((size_t)SLEN * EDIM * 2);
  float*  kv_f   = (float*)alloc((size_t)SLEN * 544 * 4);
  ushort* ckv_b  = (ushort*)alloc((size_t)SLEN * 512 * 2);
  ushort* kpe_b  = (ushort*)alloc((size_t)SLEN * 32 * 2);
  ushort* kf_b   = (ushort*)alloc((size_t)SLEN * EDIM * 2);
  ushort* vt_b   = (ushort*)alloc((size_t)SLEN * EDIM * 2);  // V^T [h*64+hd][s]
  ushort* attn_b = (ushort*)alloc((size_t)SLEN * EDIM * 2);
  char* R = alloc((size_t)SLEN * 1536 * 4);
  float* qa_f    = (float*)R;
  float* q_f     = (float*)(R + (size_t)SLEN * 512 * 4);
  float* kvdec_f = (float*)R;

  auto cast = [&](const float* src, ushort* dst, int n) {
    cast_bf16<<<dim3((n / 4 + 255) / 256), 256, 0, stream>>>((const float4*)src, dst, n / 4);
  };
  cast(x, xb, SLEN * EDIM);
  cast(Wqa, wqa_b, 512 * 1024);
  cast(Wqb, wqb_b, 1024 * 512);
  cast(Wkva, wkva_b, 544 * 1024);
  cast(Wkvb, wkvb_b, 1536 * 512);
  cast(Wo, wo_b, 1024 * 1024);
  rope_table<<<dim3((SLEN * 16 + 255) / 256), 256, 0, stream>>>(cosT, sinT);

  // q path
  gemm_bt<<<dim3(32, 4), 256, 0, stream>>>(xb, wqa_b, qa_f, SLEN, 512, 1024);
  ln_kernel<<<dim3(SLEN), 256, 0, stream>>>(qa_f, 512, qa_w, qa_b, qc_b, nullptr, nullptr, nullptr);
  gemm_bt<<<dim3(32, 8), 256, 0, stream>>>(qc_b, wqb_b, q_f, SLEN, 1024, 512);
  build_qfull<<<dim3(SLEN * EDIM / 256), 256, 0, stream>>>(q_f, cosT, sinT, qf_b);

  // kv path
  gemm_bt<<<dim3(32, 5), 256, 0, stream>>>(xb, wkva_b, kv_f, SLEN, 544, 1024);
  ln_kernel<<<dim3(SLEN), 256, 0, stream>>>(kv_f, 544, kva_w, kva_b, ckv_b, cosT, sinT, kpe_b);
  gemm_bt<<<dim3(32, 12), 256, 0, stream>>>(ckv_b, wkvb_b, kvdec_f, SLEN, 1536, 512);
  pack_kv2<<<dim3(64, 16), 256, 0, stream>>>(kvdec_f, kpe_b, kf_b, vt_b);

  // attention + output projection
  flash_attn<<<dim3(64, 16), 256, 0, stream>>>(qf_b, kf_b, vt_b, attn_b);
  gemm_bt<<<dim3(32, 8), 256, 0, stream>>>(attn_b, wo_b, out, SLEN, 1024, 1024);

  (void)in_sizes; (void)n_in; (void)out_size; (void)ws_size;
}

// Round 3
// 289.334 us; speedup vs baseline: 1.5558x; 1.1096x over previous
//
#include <hip/hip_runtime.h>
#include <hip/hip_bf16.h>
#include <stdint.h>

// ---------------- MLA decoder self-attention, bf16-MFMA pipeline ----------------
// S=4096 E=1024 H=16 HD=64 ROPE=32 NOPE=32 QR=512 KVR=512, causal.

#define SLEN 4096
#define EDIM 1024
#define NH   16

typedef __attribute__((ext_vector_type(8))) short short8;
typedef __attribute__((ext_vector_type(4))) float f32x4;

__device__ __forceinline__ ushort f2bf(float f) {
  __hip_bfloat16 h = __float2bfloat16(f);
  ushort u; __builtin_memcpy(&u, &h, 2); return u;
}

#define GLD_LDS16(g, l) __builtin_amdgcn_global_load_lds(                      \
    (const __attribute__((address_space(1))) uint32_t*)(g),                    \
    (__attribute__((address_space(3))) uint32_t*)(l), 16, 0, 0)

// ---------------- elementwise: f32 -> bf16 cast ----------------
__global__ void cast_bf16(const float4* __restrict__ in, ushort* __restrict__ out, int n4) {
  int i = blockIdx.x * blockDim.x + threadIdx.x;
  if (i >= n4) return;
  float4 v = in[i];
  ushort4 o;
  o.x = f2bf(v.x); o.y = f2bf(v.y); o.z = f2bf(v.z); o.w = f2bf(v.w);
  *(ushort4*)(out + (size_t)i * 4) = o;
}

// ---------------- rope tables: cos/sin[s][16] ----------------
__global__ void rope_table(float* __restrict__ cosT, float* __restrict__ sinT) {
  int idx = blockIdx.x * blockDim.x + threadIdx.x;
  if (idx >= SLEN * 16) return;
  int s = idx >> 4, i = idx & 15;
  float inv = expf(-((float)(2 * i) / 32.0f) * logf(10000.0f));
  float ang = (float)s * inv;
  cosT[idx] = cosf(ang);
  sinT[idx] = sinf(ang);
}

// ---------------- GEMM: C[M,N] = A[M,K] * B[N,K]^T, bf16 in / f32 out ----------------
// 64x128 tile (more blocks for small-N grids), BK=64, 4 waves (2x2 of 32x64),
// 16x16x32 bf16 MFMA, global_load_lds + XOR swizzle (src+read, LDS linear).
__global__ __launch_bounds__(256, 4) void gemm_bt(
    const ushort* __restrict__ A, const ushort* __restrict__ B, float* __restrict__ C,
    int M, int N, int K) {
  __shared__ ushort As[64 * 64];    // 8 KB
  __shared__ ushort Bs[128 * 64];   // 16 KB
  const int tid = threadIdx.x;
  const int lane = tid & 63, wave = tid >> 6;
  const int bm = blockIdx.x * 64, bn = blockIdx.y * 128;
  const int wm = (wave >> 1) * 32, wn = (wave & 1) * 64;

  f32x4 acc[2][4];
#pragma unroll
  for (int m = 0; m < 2; ++m)
#pragma unroll
    for (int n = 0; n < 4; ++n) acc[m][n] = (f32x4)0.0f;

  const int srow = lane >> 3;          // 0..7
  const int scb = (lane & 7) << 4;     // byte col
  const int srcb = scb ^ ((srow & 7) << 4);

  for (int k0 = 0; k0 < K; k0 += 64) {
    __syncthreads();
#pragma unroll
    for (int c = 0; c < 2; ++c) {   // A: 16 rows/wave
      int r = wave * 16 + c * 8 + srow;
      const ushort* ga = A + (size_t)(bm + r) * K + k0 + (srcb >> 1);
      GLD_LDS16(ga, As + (wave * 16 + c * 8) * 64);
    }
#pragma unroll
    for (int c = 0; c < 4; ++c) {   // B: 32 rows/wave
      int r = wave * 32 + c * 8 + srow;
      int rb = bn + r; if (rb >= N) rb = N - 1;
      const ushort* gb = B + (size_t)rb * K + k0 + (srcb >> 1);
      GLD_LDS16(gb, Bs + (wave * 32 + c * 8) * 64);
    }
    __syncthreads();
#pragma unroll
    for (int kk = 0; kk < 2; ++kk) {
      short8 af[2], bf[4];
#pragma unroll
      for (int m = 0; m < 2; ++m) {
        int row = wm + m * 16 + (lane & 15);
        int cb = (kk * 64 + ((lane >> 4) << 4)) ^ ((row & 7) << 4);
        af[m] = *(const short8*)((const char*)As + row * 128 + cb);
      }
#pragma unroll
      for (int n = 0; n < 4; ++n) {
        int row = wn + n * 16 + (lane & 15);
        int cb = (kk * 64 + ((lane >> 4) << 4)) ^ ((row & 7) << 4);
        bf[n] = *(const short8*)((const char*)Bs + row * 128 + cb);
      }
#pragma unroll
      for (int m = 0; m < 2; ++m)
#pragma unroll
        for (int n = 0; n < 4; ++n)
          acc[m][n] = __builtin_amdgcn_mfma_f32_16x16x32_bf16(af[m], bf[n], acc[m][n], 0, 0, 0);
    }
  }
#pragma unroll
  for (int m = 0; m < 2; ++m) {
    int gm = bm + wm + m * 16 + ((lane >> 4) << 2);
#pragma unroll
    for (int n = 0; n < 4; ++n) {
      int gn = bn + wn + n * 16 + (lane & 15);
      if (gn < N) {
#pragma unroll
        for (int r = 0; r < 4; ++r) C[(size_t)(gm + r) * N + gn] = acc[m][n][r];
      }
    }
  }
}

// ---------------- LayerNorm over 512 cols (+optional k_pe rope), bf16 out ----------------
__global__ __launch_bounds__(256) void ln_kernel(
    const float* __restrict__ in, int ldin, const float* __restrict__ w,
    const float* __restrict__ b, ushort* __restrict__ out,
    const float* __restrict__ cosT, const float* __restrict__ sinT,
    ushort* __restrict__ kpe) {
  int row = blockIdx.x, tid = threadIdx.x;
  const float* px = in + (size_t)row * ldin;
  float x0 = px[tid], x1 = px[tid + 256];
  float s = x0 + x1, sq = x0 * x0 + x1 * x1;
#pragma unroll
  for (int off = 32; off; off >>= 1) {
    s += __shfl_down(s, off);
    sq += __shfl_down(sq, off);
  }
  __shared__ float redS[4], redQ[4];
  int wave = tid >> 6, lane = tid & 63;
  if (lane == 0) { redS[wave] = s; redQ[wave] = sq; }
  __syncthreads();
  float st = redS[0] + redS[1] + redS[2] + redS[3];
  float sqt = redQ[0] + redQ[1] + redQ[2] + redQ[3];
  float mean = st * (1.0f / 512.0f);
  float var = sqt * (1.0f / 512.0f) - mean * mean;
  float rstd = rsqrtf(var + 1e-5f);
  out[(size_t)row * 512 + tid] = f2bf((x0 - mean) * rstd * w[tid] + b[tid]);
  out[(size_t)row * 512 + tid + 256] = f2bf((x1 - mean) * rstd * w[tid + 256] + b[tid + 256]);
  if (kpe != nullptr && tid < 32) {
    int p = tid >> 1;
    float xa = px[512 + 2 * p], xb = px[512 + 2 * p + 1];
    float c = cosT[(row << 4) + p], sn = sinT[(row << 4) + p];
    float v = (tid & 1) ? (xa * sn + xb * c) : (xa * c - xb * sn);
    kpe[(row << 5) + tid] = f2bf(v);
  }
}

// ---------------- q_full: copy nope + rope(q_pe), PRE-SCALED by 1/8*log2(e) ----------------
__global__ void build_qfull(const float* __restrict__ q, const float* __restrict__ cosT,
                            const float* __restrict__ sinT, ushort* __restrict__ qf) {
  const float SC = 0.125f * 1.44269504089f;  // 1/sqrt(64) * log2(e): softmax in exp2 domain
  int idx = blockIdx.x * blockDim.x + threadIdx.x;
  if (idx >= SLEN * EDIM) return;
  int d = idx & 63;
  int s = idx >> 10;
  const float* base = q + (size_t)(idx - d);
  float v;
  if (d < 32) {
    v = base[d];
  } else {
    int j = d - 32, p = j >> 1;
    float xa = base[32 + 2 * p], xb = base[33 + 2 * p];
    float c = cosT[(s << 4) + p], sn = sinT[(s << 4) + p];
    v = (j & 1) ? (xa * sn + xb * c) : (xa * c - xb * sn);
  }
  qf[idx] = f2bf(v * SC);
}

// ---------------- pack k_full + V^T (LDS-tiled transpose): vt[h][hd][s] ----------------
__global__ __launch_bounds__(256) void pack_kv2(
    const float* __restrict__ kvdec, const ushort* __restrict__ kpe,
    ushort* __restrict__ kf, ushort* __restrict__ vt) {
  __shared__ ushort T[64 * 65];
  const int tid = threadIdx.x;
  const int sb = blockIdx.x, h = blockIdx.y;
  const int s0 = sb * 64;
#pragma unroll 4
  for (int i = 0; i < 16; ++i) {
    int s_loc = i * 4 + (tid >> 6);
    int d = tid & 63;
    const float* base = kvdec + ((size_t)(s0 + s_loc) * 16 + h) * 96;
    T[d * 65 + s_loc] = f2bf(base[32 + d]);
    ushort kval = (d < 32) ? f2bf(base[d]) : kpe[((s0 + s_loc) << 5) + (d - 32)];
    kf[(size_t)(s0 + s_loc) * EDIM + h * 64 + d] = kval;
  }
  __syncthreads();
#pragma unroll 4
  for (int i = 0; i < 16; ++i) {
    int hd = i * 4 + (tid >> 6);
    int s_off = tid & 63;
    vt[(size_t)(h * 64 + hd) * SLEN + s0 + s_off] = T[hd * 65 + s_off];
  }
}

// ---------------- flash attention: causal, 64 q x 1 head per block ----------------
// 4 waves x 16 q-rows, KVBLK=64. Single-buffered K/V (25KB LDS -> high occupancy),
// scores already in log2 domain (Q pre-scaled), l-sum via MFMA with all-ones B,
// defer-max (THR=8), mask hoisted to diagonal tile.
__global__ __launch_bounds__(256, 4) void flash_attn(
    const ushort* __restrict__ Qf, const ushort* __restrict__ Kf,
    const ushort* __restrict__ Vt, ushort* __restrict__ Of) {
  __shared__ ushort Klds[64 * 64];    // 8 KB
  __shared__ ushort Vlds[64 * 64];    // 8 KB, V^T tile [hd][k]
  __shared__ ushort Plds[4][16 * 72]; // 9 KB, per-wave P
  const int tid = threadIdx.x, lane = tid & 63, wave = tid >> 6;
  const int qb = gridDim.x - 1 - blockIdx.x;  // long blocks first
  const int h = blockIdx.y;
  const int q0 = qb * 64;

  short8 aq[2];
  {
    const ushort* qrow =
        Qf + (((size_t)(q0 + wave * 16 + (lane & 15)) * 16 + h) << 6) + ((lane >> 4) << 3);
    aq[0] = *(const short8*)qrow;
    aq[1] = *(const short8*)(qrow + 32);
  }
  f32x4 oacc[4];
#pragma unroll
  for (int nf = 0; nf < 4; ++nf) oacc[nf] = (f32x4)0.0f;
  f32x4 lacc = (f32x4)0.0f;
  float mrun[4];
#pragma unroll
  for (int r = 0; r < 4; ++r) mrun[r] = -1e30f;

  short8 ones;
#pragma unroll
  for (int j = 0; j < 8; ++j) ones[j] = (short)0x3F80;  // bf16 1.0

  const int strow = wave * 16 + (lane >> 3);
  const int srcb = ((lane & 7) << 4) ^ (((lane >> 3) & 7) << 4);

  for (int kb = 0; kb <= qb; ++kb) {
    // ---- stage K and V^T (single buffer) ----
#pragma unroll
    for (int c = 0; c < 2; ++c) {
      int r = strow + c * 8;
      const ushort* gk = Kf + (((size_t)(kb * 64 + r) * 16 + h) << 6) + (srcb >> 1);
      GLD_LDS16(gk, &Klds[(wave * 16 + c * 8) * 64]);
      const ushort* gv = Vt + (size_t)(h * 64 + r) * SLEN + kb * 64 + (srcb >> 1);
      GLD_LDS16(gv, &Vlds[(wave * 16 + c * 8) * 64]);
    }
    __syncthreads();  // drains vmcnt: tile ready

    // ---- S = Q K^T (16 q x 64 k per wave), already log2-scaled ----
    f32x4 sfr[4];
#pragma unroll
    for (int n = 0; n < 4; ++n) sfr[n] = (f32x4)0.0f;
#pragma unroll
    for (int kk = 0; kk < 2; ++kk) {
#pragma unroll
      for (int n = 0; n < 4; ++n) {
        int row = n * 16 + (lane & 15);
        int cb = (kk * 64 + ((lane >> 4) << 4)) ^ ((row & 7) << 4);
        short8 bk = *(const short8*)((const char*)Klds + row * 128 + cb);
        sfr[n] = __builtin_amdgcn_mfma_f32_16x16x32_bf16(aq[kk], bk, sfr[n], 0, 0, 0);
      }
    }
    // ---- causal mask: diagonal tile only ----
    if (kb == qb) {
      const int qloc = wave * 16 + ((lane >> 4) << 2);
#pragma unroll
      for (int n = 0; n < 4; ++n) {
        int kloc = n * 16 + (lane & 15);
#pragma unroll
        for (int r = 0; r < 4; ++r)
          if (kloc > qloc + r) sfr[n][r] = -1e30f;
      }
    }
    // ---- row max ----
    float pmax[4];
#pragma unroll
    for (int r = 0; r < 4; ++r)
      pmax[r] = fmaxf(fmaxf(sfr[0][r], sfr[1][r]), fmaxf(sfr[2][r], sfr[3][r]));
#pragma unroll
    for (int r = 0; r < 4; ++r) {
#pragma unroll
      for (int off = 8; off >= 1; off >>= 1) pmax[r] = fmaxf(pmax[r], __shfl_xor(pmax[r], off));
    }
    // ---- defer-max: rescale only when max grew > 8 (log2 units) ----
    bool need = false;
#pragma unroll
    for (int r = 0; r < 4; ++r) need = need || (pmax[r] > mrun[r] + 8.0f);
    if (__any(need)) {
#pragma unroll
      for (int r = 0; r < 4; ++r) {
        float mnew = fmaxf(mrun[r], pmax[r]);
        float corr = exp2f(mrun[r] - mnew);
        mrun[r] = mnew;
        lacc[r] *= corr;
#pragma unroll
        for (int nf = 0; nf < 4; ++nf) oacc[nf][r] *= corr;
      }
    }
    // ---- P = exp2(s - m), bf16 to per-wave LDS (XOR-swizzled) ----
#pragma unroll
    for (int n = 0; n < 4; ++n) {
#pragma unroll
      for (int r = 0; r < 4; ++r) {
        float p = exp2f(sfr[n][r] - mrun[r]);
        int prow = ((lane >> 4) << 2) + r;
        int pcol = (n * 16 + (lane & 15)) ^ (8 * ((prow >> 2) & 3));
        Plds[wave][prow * 72 + pcol] = f2bf(p);
      }
    }
    // ---- O += P V ; l += P 1 (ones-MFMA keeps l in O's row layout) ----
    short8 ap[2];
    {
      int rr = lane & 15;
#pragma unroll
      for (int kk = 0; kk < 2; ++kk) {
        int koff = (kk * 32 + ((lane >> 4) << 3)) ^ (8 * ((rr >> 2) & 3));
        ap[kk] = *(const short8*)&Plds[wave][rr * 72 + koff];
      }
    }
#pragma unroll
    for (int nf = 0; nf < 4; ++nf) {
#pragma unroll
      for (int kk = 0; kk < 2; ++kk) {
        int row = nf * 16 + (lane & 15);
        int cb = (kk * 64 + ((lane >> 4) << 4)) ^ ((row & 7) << 4);
        short8 bv = *(const short8*)((const char*)Vlds + row * 128 + cb);
        oacc[nf] = __builtin_amdgcn_mfma_f32_16x16x32_bf16(ap[kk], bv, oacc[nf], 0, 0, 0);
      }
    }
    lacc = __builtin_amdgcn_mfma_f32_16x16x32_bf16(ap[0], ones, lacc, 0, 0, 0);
    lacc = __builtin_amdgcn_mfma_f32_16x16x32_bf16(ap[1], ones, lacc, 0, 0, 0);
    __syncthreads();  // K/V reads complete before next stage overwrites
  }
  // ---- epilogue: O /= l ----
#pragma unroll
  for (int nf = 0; nf < 4; ++nf) {
#pragma unroll
    for (int r = 0; r < 4; ++r) {
      int gq = q0 + wave * 16 + ((lane >> 4) << 2) + r;
      int gd = h * 64 + nf * 16 + (lane & 15);
      Of[(size_t)gq * EDIM + gd] = f2bf(oacc[nf][r] / lacc[r]);
    }
  }
}

// ---------------- launcher ----------------
extern "C" void kernel_launch(void* const* d_in, const int* in_sizes, int n_in,
                              void* d_out, int out_size, void* d_ws, size_t ws_size,
                              hipStream_t stream) {
  const float* x     = (const float*)d_in[0];
  const float* Wqa   = (const float*)d_in[2];
  const float* qa_w  = (const float*)d_in[3];
  const float* qa_b  = (const float*)d_in[4];
  const float* Wqb   = (const float*)d_in[5];
  const float* Wkva  = (const float*)d_in[6];
  const float* kva_w = (const float*)d_in[7];
  const float* kva_b = (const float*)d_in[8];
  const float* Wkvb  = (const float*)d_in[9];
  const float* Wo    = (const float*)d_in[10];
  float* out = (float*)d_out;

  char* ws = (char*)d_ws;
  size_t off = 0;
  auto alloc = [&](size_t bytes) {
    char* p = ws + off;
    off += (bytes + 255) & ~(size_t)255;
    return p;
  };
  ushort* xb      = (ushort*)alloc((size_t)SLEN * EDIM * 2);
  ushort* wqkva_b = (ushort*)alloc((size_t)1056 * 1024 * 2);  // Wqa rows 0..511, Wkva rows 512..1055
  ushort* wqb_b   = (ushort*)alloc((size_t)1024 * 512 * 2);
  ushort* wkvb_b  = (ushort*)alloc((size_t)1536 * 512 * 2);
  ushort* wo_b    = (ushort*)alloc((size_t)1024 * 1024 * 2);
  float*  cosT    = (float*)alloc((size_t)SLEN * 16 * 4);
  float*  sinT    = (float*)alloc((size_t)SLEN * 16 * 4);
  ushort* qc_b    = (ushort*)alloc((size_t)SLEN * 512 * 2);
  ushort* qf_b    = (ushort*)alloc((size_t)SLEN * EDIM * 2);
  ushort* ckv_b   = (ushort*)alloc((size_t)SLEN * 512 * 2);
  ushort* kpe_b   = (ushort*)alloc((size_t)SLEN * 32 * 2);
  ushort* kf_b    = (ushort*)alloc((size_t)SLEN * EDIM * 2);
  ushort* vt_b    = (ushort*)alloc((size_t)SLEN * EDIM * 2);
  ushort* attn_b  = (ushort*)alloc((size_t)SLEN * EDIM * 2);
  // one shared f32 scratch: qakv [4096][1056] -> q [4096][1024] -> kvdec [4096][1536]
  char* R = alloc((size_t)SLEN * 1536 * 4);
  float* qakv_f  = (float*)R;
  float* q_f     = (float*)R;
  float* kvdec_f = (float*)R;

  auto cast = [&](const float* src, ushort* dst, int n) {
    cast_bf16<<<dim3((n / 4 + 255) / 256), 256, 0, stream>>>((const float4*)src, dst, n / 4);
  };
  cast(x, xb, SLEN * EDIM);
  cast(Wqa, wqkva_b, 512 * 1024);
  cast(Wkva, wqkva_b + (size_t)512 * 1024, 544 * 1024);
  cast(Wqb, wqb_b, 1024 * 512);
  cast(Wkvb, wkvb_b, 1536 * 512);
  cast(Wo, wo_b, 1024 * 1024);
  rope_table<<<dim3((SLEN * 16 + 255) / 256), 256, 0, stream>>>(cosT, sinT);

  // merged qa+kva projection: [4096][1056]
  gemm_bt<<<dim3(64, 9), 256, 0, stream>>>(xb, wqkva_b, qakv_f, SLEN, 1056, 1024);
  ln_kernel<<<dim3(SLEN), 256, 0, stream>>>(qakv_f, 1056, qa_w, qa_b, qc_b, nullptr, nullptr, nullptr);
  ln_kernel<<<dim3(SLEN), 256, 0, stream>>>(qakv_f + 512, 1056, kva_w, kva_b, ckv_b, cosT, sinT, kpe_b);
  // qakv dead -> reuse R for q_f
  gemm_bt<<<dim3(64, 8), 256, 0, stream>>>(qc_b, wqb_b, q_f, SLEN, 1024, 512);
  build_qfull<<<dim3(SLEN * EDIM / 256), 256, 0, stream>>>(q_f, cosT, sinT, qf_b);
  // q_f dead -> reuse R for kvdec
  gemm_bt<<<dim3(64, 12), 256, 0, stream>>>(ckv_b, wkvb_b, kvdec_f, SLEN, 1536, 512);
  pack_kv2<<<dim3(64, 16), 256, 0, stream>>>(kvdec_f, kpe_b, kf_b, vt_b);

  flash_attn<<<dim3(64, 16), 256, 0, stream>>>(qf_b, kf_b, vt_b, attn_b);
  gemm_bt<<<dim3(64, 8), 256, 0, stream>>>(attn_b, wo_b, out, SLEN, 1024, 1024);

  (void)in_sizes; (void)n_in; (void)out_size; (void)ws_size;
}

// Round 4
// 248.767 us; speedup vs baseline: 1.8095x; 1.1631x over previous
//
#include <hip/hip_runtime.h>
#include <hip/hip_bf16.h>
#include <stdint.h>

// ---------------- MLA decoder self-attention, bf16-MFMA pipeline ----------------
// S=4096 E=1024 H=16 HD=64 ROPE=32 NOPE=32 QR=512 KVR=512, causal.
// R3: KV-split flash attention (flash-decoding): 160 (qb,chunk) x 16 heads partial
// blocks (max 16 tiles each) + f32 partial O/m/l + combine kernel.

#define SLEN 4096
#define EDIM 1024
#define NH   16
#define NPAIR 160   // sum over qb of floor(qb/16)+1

typedef __attribute__((ext_vector_type(8))) short short8;
typedef __attribute__((ext_vector_type(4))) float f32x4;

__device__ __forceinline__ ushort f2bf(float f) {
  __hip_bfloat16 h = __float2bfloat16(f);
  ushort u; __builtin_memcpy(&u, &h, 2); return u;
}

#define GLD_LDS16(g, l) __builtin_amdgcn_global_load_lds(                      \
    (const __attribute__((address_space(1))) uint32_t*)(g),                    \
    (__attribute__((address_space(3))) uint32_t*)(l), 16, 0, 0)

// ---------------- elementwise: f32 -> bf16 cast ----------------
__global__ void cast_bf16(const float4* __restrict__ in, ushort* __restrict__ out, int n4) {
  int i = blockIdx.x * blockDim.x + threadIdx.x;
  if (i >= n4) return;
  float4 v = in[i];
  ushort4 o;
  o.x = f2bf(v.x); o.y = f2bf(v.y); o.z = f2bf(v.z); o.w = f2bf(v.w);
  *(ushort4*)(out + (size_t)i * 4) = o;
}

// ---------------- rope tables: cos/sin[s][16] ----------------
__global__ void rope_table(float* __restrict__ cosT, float* __restrict__ sinT) {
  int idx = blockIdx.x * blockDim.x + threadIdx.x;
  if (idx >= SLEN * 16) return;
  int s = idx >> 4, i = idx & 15;
  float inv = expf(-((float)(2 * i) / 32.0f) * logf(10000.0f));
  float ang = (float)s * inv;
  cosT[idx] = cosf(ang);
  sinT[idx] = sinf(ang);
}

// ---------------- GEMM: C[M,N] = A[M,K] * B[N,K]^T, bf16 in / f32 out ----------------
__global__ __launch_bounds__(256, 4) void gemm_bt(
    const ushort* __restrict__ A, const ushort* __restrict__ B, float* __restrict__ C,
    int M, int N, int K) {
  __shared__ ushort As[64 * 64];
  __shared__ ushort Bs[128 * 64];
  const int tid = threadIdx.x;
  const int lane = tid & 63, wave = tid >> 6;
  const int bm = blockIdx.x * 64, bn = blockIdx.y * 128;
  const int wm = (wave >> 1) * 32, wn = (wave & 1) * 64;

  f32x4 acc[2][4];
#pragma unroll
  for (int m = 0; m < 2; ++m)
#pragma unroll
    for (int n = 0; n < 4; ++n) acc[m][n] = (f32x4)0.0f;

  const int srow = lane >> 3;
  const int scb = (lane & 7) << 4;
  const int srcb = scb ^ ((srow & 7) << 4);

  for (int k0 = 0; k0 < K; k0 += 64) {
    __syncthreads();
#pragma unroll
    for (int c = 0; c < 2; ++c) {
      int r = wave * 16 + c * 8 + srow;
      const ushort* ga = A + (size_t)(bm + r) * K + k0 + (srcb >> 1);
      GLD_LDS16(ga, As + (wave * 16 + c * 8) * 64);
    }
#pragma unroll
    for (int c = 0; c < 4; ++c) {
      int r = wave * 32 + c * 8 + srow;
      int rb = bn + r; if (rb >= N) rb = N - 1;
      const ushort* gb = B + (size_t)rb * K + k0 + (srcb >> 1);
      GLD_LDS16(gb, Bs + (wave * 32 + c * 8) * 64);
    }
    __syncthreads();
#pragma unroll
    for (int kk = 0; kk < 2; ++kk) {
      short8 af[2], bf[4];
#pragma unroll
      for (int m = 0; m < 2; ++m) {
        int row = wm + m * 16 + (lane & 15);
        int cb = (kk * 64 + ((lane >> 4) << 4)) ^ ((row & 7) << 4);
        af[m] = *(const short8*)((const char*)As + row * 128 + cb);
      }
#pragma unroll
      for (int n = 0; n < 4; ++n) {
        int row = wn + n * 16 + (lane & 15);
        int cb = (kk * 64 + ((lane >> 4) << 4)) ^ ((row & 7) << 4);
        bf[n] = *(const short8*)((const char*)Bs + row * 128 + cb);
      }
#pragma unroll
      for (int m = 0; m < 2; ++m)
#pragma unroll
        for (int n = 0; n < 4; ++n)
          acc[m][n] = __builtin_amdgcn_mfma_f32_16x16x32_bf16(af[m], bf[n], acc[m][n], 0, 0, 0);
    }
  }
#pragma unroll
  for (int m = 0; m < 2; ++m) {
    int gm = bm + wm + m * 16 + ((lane >> 4) << 2);
#pragma unroll
    for (int n = 0; n < 4; ++n) {
      int gn = bn + wn + n * 16 + (lane & 15);
      if (gn < N) {
#pragma unroll
        for (int r = 0; r < 4; ++r) C[(size_t)(gm + r) * N + gn] = acc[m][n][r];
      }
    }
  }
}

// ---------------- LayerNorm over 512 cols (+optional k_pe rope), bf16 out ----------------
__global__ __launch_bounds__(256) void ln_kernel(
    const float* __restrict__ in, int ldin, const float* __restrict__ w,
    const float* __restrict__ b, ushort* __restrict__ out,
    const float* __restrict__ cosT, const float* __restrict__ sinT,
    ushort* __restrict__ kpe) {
  int row = blockIdx.x, tid = threadIdx.x;
  const float* px = in + (size_t)row * ldin;
  float x0 = px[tid], x1 = px[tid + 256];
  float s = x0 + x1, sq = x0 * x0 + x1 * x1;
#pragma unroll
  for (int off = 32; off; off >>= 1) {
    s += __shfl_down(s, off);
    sq += __shfl_down(sq, off);
  }
  __shared__ float redS[4], redQ[4];
  int wave = tid >> 6, lane = tid & 63;
  if (lane == 0) { redS[wave] = s; redQ[wave] = sq; }
  __syncthreads();
  float st = redS[0] + redS[1] + redS[2] + redS[3];
  float sqt = redQ[0] + redQ[1] + redQ[2] + redQ[3];
  float mean = st * (1.0f / 512.0f);
  float var = sqt * (1.0f / 512.0f) - mean * mean;
  float rstd = rsqrtf(var + 1e-5f);
  out[(size_t)row * 512 + tid] = f2bf((x0 - mean) * rstd * w[tid] + b[tid]);
  out[(size_t)row * 512 + tid + 256] = f2bf((x1 - mean) * rstd * w[tid + 256] + b[tid + 256]);
  if (kpe != nullptr && tid < 32) {
    int p = tid >> 1;
    float xa = px[512 + 2 * p], xb = px[512 + 2 * p + 1];
    float c = cosT[(row << 4) + p], sn = sinT[(row << 4) + p];
    float v = (tid & 1) ? (xa * sn + xb * c) : (xa * c - xb * sn);
    kpe[(row << 5) + tid] = f2bf(v);
  }
}

// ---------------- q_full: copy nope + rope(q_pe), PRE-SCALED by 1/8*log2(e) ----------------
__global__ void build_qfull(const float* __restrict__ q, const float* __restrict__ cosT,
                            const float* __restrict__ sinT, ushort* __restrict__ qf) {
  const float SC = 0.125f * 1.44269504089f;
  int idx = blockIdx.x * blockDim.x + threadIdx.x;
  if (idx >= SLEN * EDIM) return;
  int d = idx & 63;
  int s = idx >> 10;
  const float* base = q + (size_t)(idx - d);
  float v;
  if (d < 32) {
    v = base[d];
  } else {
    int j = d - 32, p = j >> 1;
    float xa = base[32 + 2 * p], xb = base[33 + 2 * p];
    float c = cosT[(s << 4) + p], sn = sinT[(s << 4) + p];
    v = (j & 1) ? (xa * sn + xb * c) : (xa * c - xb * sn);
  }
  qf[idx] = f2bf(v * SC);
}

// ---------------- pack k_full + V^T (LDS-tiled transpose): vt[h][hd][s] ----------------
__global__ __launch_bounds__(256) void pack_kv2(
    const float* __restrict__ kvdec, const ushort* __restrict__ kpe,
    ushort* __restrict__ kf, ushort* __restrict__ vt) {
  __shared__ ushort T[64 * 65];
  const int tid = threadIdx.x;
  const int sb = blockIdx.x, h = blockIdx.y;
  const int s0 = sb * 64;
#pragma unroll 4
  for (int i = 0; i < 16; ++i) {
    int s_loc = i * 4 + (tid >> 6);
    int d = tid & 63;
    const float* base = kvdec + ((size_t)(s0 + s_loc) * 16 + h) * 96;
    T[d * 65 + s_loc] = f2bf(base[32 + d]);
    ushort kval = (d < 32) ? f2bf(base[d]) : kpe[((s0 + s_loc) << 5) + (d - 32)];
    kf[(size_t)(s0 + s_loc) * EDIM + h * 64 + d] = kval;
  }
  __syncthreads();
#pragma unroll 4
  for (int i = 0; i < 16; ++i) {
    int hd = i * 4 + (tid >> 6);
    int s_off = tid & 63;
    vt[(size_t)(h * 64 + hd) * SLEN + s0 + s_off] = T[hd * 65 + s_off];
  }
}

// ---------------- flash attention, KV-split partials ----------------
// (qb, chunk) pairs flattened: qb in [16g,16g+15] has g+1 chunks of 16 tiles.
// Each block: <=16 KV tiles; writes raw O (f32), m, l. Longest groups dispatch first.
__global__ __launch_bounds__(256, 4) void flash_part(
    const ushort* __restrict__ Qf, const ushort* __restrict__ Kf,
    const ushort* __restrict__ Vt, float* __restrict__ Opart, float* __restrict__ MLpart) {
  __shared__ ushort Klds[64 * 64];
  __shared__ ushort Vlds[64 * 64];
  __shared__ ushort Plds[4][16 * 72];
  const int tid = threadIdx.x, lane = tid & 63, wave = tid >> 6;
  const int p = NPAIR - 1 - blockIdx.x;   // big-qb groups first
  const int h = blockIdx.y;
  // decode p -> (qb, chunk)
  int qb, ck;
  if (p < 16)      { qb = p;               ck = 0; }
  else if (p < 48) { int j = p - 16; qb = 16 + (j >> 1); ck = j & 1; }
  else if (p < 96) { int j = p - 48; qb = 32 + j / 3;    ck = j - 3 * (j / 3); }
  else             { int j = p - 96; qb = 48 + (j >> 2); ck = j & 3; }
  const int q0 = qb * 64;
  const int t0 = ck * 16;
  const int t1 = min(t0 + 16, qb + 1);

  short8 aq[2];
  {
    const ushort* qrow =
        Qf + (((size_t)(q0 + wave * 16 + (lane & 15)) * 16 + h) << 6) + ((lane >> 4) << 3);
    aq[0] = *(const short8*)qrow;
    aq[1] = *(const short8*)(qrow + 32);
  }
  f32x4 oacc[4];
#pragma unroll
  for (int nf = 0; nf < 4; ++nf) oacc[nf] = (f32x4)0.0f;
  f32x4 lacc = (f32x4)0.0f;
  float mrun[4];
#pragma unroll
  for (int r = 0; r < 4; ++r) mrun[r] = -1e30f;

  short8 ones;
#pragma unroll
  for (int j = 0; j < 8; ++j) ones[j] = (short)0x3F80;

  const int strow = wave * 16 + (lane >> 3);
  const int srcb = ((lane & 7) << 4) ^ (((lane >> 3) & 7) << 4);

  for (int kb = t0; kb < t1; ++kb) {
#pragma unroll
    for (int c = 0; c < 2; ++c) {
      int r = strow + c * 8;
      const ushort* gk = Kf + (((size_t)(kb * 64 + r) * 16 + h) << 6) + (srcb >> 1);
      GLD_LDS16(gk, &Klds[(wave * 16 + c * 8) * 64]);
      const ushort* gv = Vt + (size_t)(h * 64 + r) * SLEN + kb * 64 + (srcb >> 1);
      GLD_LDS16(gv, &Vlds[(wave * 16 + c * 8) * 64]);
    }
    __syncthreads();

    f32x4 sfr[4];
#pragma unroll
    for (int n = 0; n < 4; ++n) sfr[n] = (f32x4)0.0f;
#pragma unroll
    for (int kk = 0; kk < 2; ++kk) {
#pragma unroll
      for (int n = 0; n < 4; ++n) {
        int row = n * 16 + (lane & 15);
        int cb = (kk * 64 + ((lane >> 4) << 4)) ^ ((row & 7) << 4);
        short8 bk = *(const short8*)((const char*)Klds + row * 128 + cb);
        sfr[n] = __builtin_amdgcn_mfma_f32_16x16x32_bf16(aq[kk], bk, sfr[n], 0, 0, 0);
      }
    }
    if (kb == qb) {
      const int qloc = wave * 16 + ((lane >> 4) << 2);
#pragma unroll
      for (int n = 0; n < 4; ++n) {
        int kloc = n * 16 + (lane & 15);
#pragma unroll
        for (int r = 0; r < 4; ++r)
          if (kloc > qloc + r) sfr[n][r] = -1e30f;
      }
    }
    float pmax[4];
#pragma unroll
    for (int r = 0; r < 4; ++r)
      pmax[r] = fmaxf(fmaxf(sfr[0][r], sfr[1][r]), fmaxf(sfr[2][r], sfr[3][r]));
#pragma unroll
    for (int r = 0; r < 4; ++r) {
#pragma unroll
      for (int off = 8; off >= 1; off >>= 1) pmax[r] = fmaxf(pmax[r], __shfl_xor(pmax[r], off));
    }
    bool need = false;
#pragma unroll
    for (int r = 0; r < 4; ++r) need = need || (pmax[r] > mrun[r] + 8.0f);
    if (__any(need)) {
#pragma unroll
      for (int r = 0; r < 4; ++r) {
        float mnew = fmaxf(mrun[r], pmax[r]);
        float corr = exp2f(mrun[r] - mnew);
        mrun[r] = mnew;
        lacc[r] *= corr;
#pragma unroll
        for (int nf = 0; nf < 4; ++nf) oacc[nf][r] *= corr;
      }
    }
#pragma unroll
    for (int n = 0; n < 4; ++n) {
#pragma unroll
      for (int r = 0; r < 4; ++r) {
        float pv = exp2f(sfr[n][r] - mrun[r]);
        int prow = ((lane >> 4) << 2) + r;
        int pcol = (n * 16 + (lane & 15)) ^ (8 * ((prow >> 2) & 3));
        Plds[wave][prow * 72 + pcol] = f2bf(pv);
      }
    }
    short8 ap[2];
    {
      int rr = lane & 15;
#pragma unroll
      for (int kk = 0; kk < 2; ++kk) {
        int koff = (kk * 32 + ((lane >> 4) << 3)) ^ (8 * ((rr >> 2) & 3));
        ap[kk] = *(const short8*)&Plds[wave][rr * 72 + koff];
      }
    }
#pragma unroll
    for (int nf = 0; nf < 4; ++nf) {
#pragma unroll
      for (int kk = 0; kk < 2; ++kk) {
        int row = nf * 16 + (lane & 15);
        int cb = (kk * 64 + ((lane >> 4) << 4)) ^ ((row & 7) << 4);
        short8 bv = *(const short8*)((const char*)Vlds + row * 128 + cb);
        oacc[nf] = __builtin_amdgcn_mfma_f32_16x16x32_bf16(ap[kk], bv, oacc[nf], 0, 0, 0);
      }
    }
    lacc = __builtin_amdgcn_mfma_f32_16x16x32_bf16(ap[0], ones, lacc, 0, 0, 0);
    lacc = __builtin_amdgcn_mfma_f32_16x16x32_bf16(ap[1], ones, lacc, 0, 0, 0);
    __syncthreads();
  }
  // ---- write raw partials ----
  const size_t pb = (size_t)h * NPAIR + p;
#pragma unroll
  for (int nf = 0; nf < 4; ++nf) {
#pragma unroll
    for (int r = 0; r < 4; ++r) {
      int row = wave * 16 + ((lane >> 4) << 2) + r;
      int d = nf * 16 + (lane & 15);
      Opart[(pb * 64 + row) * 64 + d] = oacc[nf][r];
    }
  }
  if ((lane & 15) == 0) {
#pragma unroll
    for (int r = 0; r < 4; ++r) {
      int row = wave * 16 + ((lane >> 4) << 2) + r;
      MLpart[pb * 128 + row] = mrun[r];
      MLpart[pb * 128 + 64 + row] = lacc[r];
    }
  }
}

// ---------------- combine partials -> attn bf16 [s][h*64+d] ----------------
__global__ __launch_bounds__(256) void flash_combine(
    const float* __restrict__ Opart, const float* __restrict__ MLpart,
    ushort* __restrict__ attn) {
  const int qb = blockIdx.x, h = blockIdx.y;
  const int g = qb >> 4, n = g + 1;
  const int base = (g == 0 ? 0 : g == 1 ? 16 : g == 2 ? 48 : 96) + (qb - (g << 4)) * n;
  __shared__ float mS[4][64], lS[4][64];
  const int tid = threadIdx.x;
  for (int i = tid; i < n * 64; i += 256) {
    int part = i >> 6, row = i & 63;
    size_t pb = (size_t)h * NPAIR + base + part;
    mS[part][row] = MLpart[pb * 128 + row];
    lS[part][row] = MLpart[pb * 128 + 64 + row];
  }
  __syncthreads();
  const int d = tid & 63, rg = tid >> 6;
#pragma unroll 4
  for (int k = 0; k < 16; ++k) {
    int row = rg * 16 + k;
    float M = mS[0][row];
    for (int i = 1; i < n; ++i) M = fmaxf(M, mS[i][row]);
    float L = 0.0f, acc = 0.0f;
    for (int i = 0; i < n; ++i) {
      float w = exp2f(mS[i][row] - M);
      L += lS[i][row] * w;
      acc += Opart[(((size_t)h * NPAIR + base + i) * 64 + row) * 64 + d] * w;
    }
    attn[(size_t)(qb * 64 + row) * EDIM + h * 64 + d] = f2bf(acc / L);
  }
}

// ---------------- launcher ----------------
extern "C" void kernel_launch(void* const* d_in, const int* in_sizes, int n_in,
                              void* d_out, int out_size, void* d_ws, size_t ws_size,
                              hipStream_t stream) {
  const float* x     = (const float*)d_in[0];
  const float* Wqa   = (const float*)d_in[2];
  const float* qa_w  = (const float*)d_in[3];
  const float* qa_b  = (const float*)d_in[4];
  const float* Wqb   = (const float*)d_in[5];
  const float* Wkva  = (const float*)d_in[6];
  const float* kva_w = (const float*)d_in[7];
  const float* kva_b = (const float*)d_in[8];
  const float* Wkvb  = (const float*)d_in[9];
  const float* Wo    = (const float*)d_in[10];
  float* out = (float*)d_out;

  char* ws = (char*)d_ws;
  size_t off = 0;
  auto alloc = [&](size_t bytes) {
    char* p = ws + off;
    off += (bytes + 255) & ~(size_t)255;
    return p;
  };
  ushort* xb      = (ushort*)alloc((size_t)SLEN * EDIM * 2);
  ushort* wqkva_b = (ushort*)alloc((size_t)1056 * 1024 * 2);
  ushort* wqb_b   = (ushort*)alloc((size_t)1024 * 512 * 2);
  ushort* wkvb_b  = (ushort*)alloc((size_t)1536 * 512 * 2);
  ushort* wo_b    = (ushort*)alloc((size_t)1024 * 1024 * 2);
  float*  cosT    = (float*)alloc((size_t)SLEN * 16 * 4);
  float*  sinT    = (float*)alloc((size_t)SLEN * 16 * 4);
  ushort* qc_b    = (ushort*)alloc((size_t)SLEN * 512 * 2);
  ushort* qf_b    = (ushort*)alloc((size_t)SLEN * EDIM * 2);
  ushort* ckv_b   = (ushort*)alloc((size_t)SLEN * 512 * 2);
  ushort* kpe_b   = (ushort*)alloc((size_t)SLEN * 32 * 2);
  ushort* kf_b    = (ushort*)alloc((size_t)SLEN * EDIM * 2);
  ushort* vt_b    = (ushort*)alloc((size_t)SLEN * EDIM * 2);
  ushort* attn_b  = (ushort*)alloc((size_t)SLEN * EDIM * 2);
  // shared scratch region: f32 intermediates (dead before flash) then partials
  size_t interm = (size_t)SLEN * 1536 * 4;                      // 25.2 MB
  size_t parts  = (size_t)NH * NPAIR * 64 * 64 * 4 + (size_t)NH * NPAIR * 128 * 4;
  char* R = alloc(interm > parts ? interm : parts);
  float* qakv_f  = (float*)R;
  float* q_f     = (float*)R;
  float* kvdec_f = (float*)R;
  float* Opart   = (float*)R;
  float* MLpart  = (float*)(R + (size_t)NH * NPAIR * 64 * 64 * 4);

  auto cast = [&](const float* src, ushort* dst, int n) {
    cast_bf16<<<dim3((n / 4 + 255) / 256), 256, 0, stream>>>((const float4*)src, dst, n / 4);
  };
  cast(x, xb, SLEN * EDIM);
  cast(Wqa, wqkva_b, 512 * 1024);
  cast(Wkva, wqkva_b + (size_t)512 * 1024, 544 * 1024);
  cast(Wqb, wqb_b, 1024 * 512);
  cast(Wkvb, wkvb_b, 1536 * 512);
  cast(Wo, wo_b, 1024 * 1024);
  rope_table<<<dim3((SLEN * 16 + 255) / 256), 256, 0, stream>>>(cosT, sinT);

  gemm_bt<<<dim3(64, 9), 256, 0, stream>>>(xb, wqkva_b, qakv_f, SLEN, 1056, 1024);
  ln_kernel<<<dim3(SLEN), 256, 0, stream>>>(qakv_f, 1056, qa_w, qa_b, qc_b, nullptr, nullptr, nullptr);
  ln_kernel<<<dim3(SLEN), 256, 0, stream>>>(qakv_f + 512, 1056, kva_w, kva_b, ckv_b, cosT, sinT, kpe_b);
  gemm_bt<<<dim3(64, 8), 256, 0, stream>>>(qc_b, wqb_b, q_f, SLEN, 1024, 512);
  build_qfull<<<dim3(SLEN * EDIM / 256), 256, 0, stream>>>(q_f, cosT, sinT, qf_b);
  gemm_bt<<<dim3(64, 12), 256, 0, stream>>>(ckv_b, wkvb_b, kvdec_f, SLEN, 1536, 512);
  pack_kv2<<<dim3(64, 16), 256, 0, stream>>>(kvdec_f, kpe_b, kf_b, vt_b);

  flash_part<<<dim3(NPAIR, 16), 256, 0, stream>>>(qf_b, kf_b, vt_b, Opart, MLpart);
  flash_combine<<<dim3(64, 16), 256, 0, stream>>>(Opart, MLpart, attn_b);
  gemm_bt<<<dim3(64, 8), 256, 0, stream>>>(attn_b, wo_b, out, SLEN, 1024, 1024);

  (void)in_sizes; (void)n_in; (void)out_size; (void)ws_size;
}

// Round 5
// 220.742 us; speedup vs baseline: 2.0392x; 1.1270x over previous
//
#include <hip/hip_runtime.h>
#include <hip/hip_bf16.h>
#include <stdint.h>

// ---------------- MLA decoder self-attention, bf16-MFMA pipeline ----------------
// S=4096 E=1024 H=16 HD=64 ROPE=32 NOPE=32 QR=512 KVR=512, causal.
// R4: swapped-QK^T flash (S^T = K*Q) -> lane-local softmax; V k-axis permuted so
// P stays in registers (no Plds round-trip). KV-split partials + combine.

#define SLEN 4096
#define EDIM 1024
#define NH   16
#define NPAIR 160   // sum over qb of floor(qb/16)+1

typedef __attribute__((ext_vector_type(8))) short short8;
typedef __attribute__((ext_vector_type(4))) float f32x4;

__device__ __forceinline__ ushort f2bf(float f) {
  __hip_bfloat16 h = __float2bfloat16(f);
  ushort u; __builtin_memcpy(&u, &h, 2); return u;
}

__device__ __forceinline__ uint32_t cvt_pk_bf16(float lo, float hi) {
  uint32_t r;
  asm("v_cvt_pk_bf16_f32 %0, %1, %2" : "=v"(r) : "v"(lo), "v"(hi));
  return r;
}

#define GLD_LDS16(g, l) __builtin_amdgcn_global_load_lds(                      \
    (const __attribute__((address_space(1))) uint32_t*)(g),                    \
    (__attribute__((address_space(3))) uint32_t*)(l), 16, 0, 0)

// ---------------- elementwise: f32 -> bf16 cast ----------------
__global__ void cast_bf16(const float4* __restrict__ in, ushort* __restrict__ out, int n4) {
  int i = blockIdx.x * blockDim.x + threadIdx.x;
  if (i >= n4) return;
  float4 v = in[i];
  ushort4 o;
  o.x = f2bf(v.x); o.y = f2bf(v.y); o.z = f2bf(v.z); o.w = f2bf(v.w);
  *(ushort4*)(out + (size_t)i * 4) = o;
}

// ---------------- rope tables: cos/sin[s][16] ----------------
__global__ void rope_table(float* __restrict__ cosT, float* __restrict__ sinT) {
  int idx = blockIdx.x * blockDim.x + threadIdx.x;
  if (idx >= SLEN * 16) return;
  int s = idx >> 4, i = idx & 15;
  float inv = expf(-((float)(2 * i) / 32.0f) * logf(10000.0f));
  float ang = (float)s * inv;
  cosT[idx] = cosf(ang);
  sinT[idx] = sinf(ang);
}

// ---------------- GEMM: C[M,N] = A[M,K] * B[N,K]^T, bf16 in / f32 out ----------------
__global__ __launch_bounds__(256, 4) void gemm_bt(
    const ushort* __restrict__ A, const ushort* __restrict__ B, float* __restrict__ C,
    int M, int N, int K) {
  __shared__ ushort As[64 * 64];
  __shared__ ushort Bs[128 * 64];
  const int tid = threadIdx.x;
  const int lane = tid & 63, wave = tid >> 6;
  const int bm = blockIdx.x * 64, bn = blockIdx.y * 128;
  const int wm = (wave >> 1) * 32, wn = (wave & 1) * 64;

  f32x4 acc[2][4];
#pragma unroll
  for (int m = 0; m < 2; ++m)
#pragma unroll
    for (int n = 0; n < 4; ++n) acc[m][n] = (f32x4)0.0f;

  const int srow = lane >> 3;
  const int scb = (lane & 7) << 4;
  const int srcb = scb ^ ((srow & 7) << 4);

  for (int k0 = 0; k0 < K; k0 += 64) {
    __syncthreads();
#pragma unroll
    for (int c = 0; c < 2; ++c) {
      int r = wave * 16 + c * 8 + srow;
      const ushort* ga = A + (size_t)(bm + r) * K + k0 + (srcb >> 1);
      GLD_LDS16(ga, As + (wave * 16 + c * 8) * 64);
    }
#pragma unroll
    for (int c = 0; c < 4; ++c) {
      int r = wave * 32 + c * 8 + srow;
      int rb = bn + r; if (rb >= N) rb = N - 1;
      const ushort* gb = B + (size_t)rb * K + k0 + (srcb >> 1);
      GLD_LDS16(gb, Bs + (wave * 32 + c * 8) * 64);
    }
    __syncthreads();
#pragma unroll
    for (int kk = 0; kk < 2; ++kk) {
      short8 af[2], bf[4];
#pragma unroll
      for (int m = 0; m < 2; ++m) {
        int row = wm + m * 16 + (lane & 15);
        int cb = (kk * 64 + ((lane >> 4) << 4)) ^ ((row & 7) << 4);
        af[m] = *(const short8*)((const char*)As + row * 128 + cb);
      }
#pragma unroll
      for (int n = 0; n < 4; ++n) {
        int row = wn + n * 16 + (lane & 15);
        int cb = (kk * 64 + ((lane >> 4) << 4)) ^ ((row & 7) << 4);
        bf[n] = *(const short8*)((const char*)Bs + row * 128 + cb);
      }
#pragma unroll
      for (int m = 0; m < 2; ++m)
#pragma unroll
        for (int n = 0; n < 4; ++n)
          acc[m][n] = __builtin_amdgcn_mfma_f32_16x16x32_bf16(af[m], bf[n], acc[m][n], 0, 0, 0);
    }
  }
#pragma unroll
  for (int m = 0; m < 2; ++m) {
    int gm = bm + wm + m * 16 + ((lane >> 4) << 2);
#pragma unroll
    for (int n = 0; n < 4; ++n) {
      int gn = bn + wn + n * 16 + (lane & 15);
      if (gn < N) {
#pragma unroll
        for (int r = 0; r < 4; ++r) C[(size_t)(gm + r) * N + gn] = acc[m][n][r];
      }
    }
  }
}

// ---------------- LayerNorm over 512 cols (+optional k_pe rope), bf16 out ----------------
__global__ __launch_bounds__(256) void ln_kernel(
    const float* __restrict__ in, int ldin, const float* __restrict__ w,
    const float* __restrict__ b, ushort* __restrict__ out,
    const float* __restrict__ cosT, const float* __restrict__ sinT,
    ushort* __restrict__ kpe) {
  int row = blockIdx.x, tid = threadIdx.x;
  const float* px = in + (size_t)row * ldin;
  float x0 = px[tid], x1 = px[tid + 256];
  float s = x0 + x1, sq = x0 * x0 + x1 * x1;
#pragma unroll
  for (int off = 32; off; off >>= 1) {
    s += __shfl_down(s, off);
    sq += __shfl_down(sq, off);
  }
  __shared__ float redS[4], redQ[4];
  int wave = tid >> 6, lane = tid & 63;
  if (lane == 0) { redS[wave] = s; redQ[wave] = sq; }
  __syncthreads();
  float st = redS[0] + redS[1] + redS[2] + redS[3];
  float sqt = redQ[0] + redQ[1] + redQ[2] + redQ[3];
  float mean = st * (1.0f / 512.0f);
  float var = sqt * (1.0f / 512.0f) - mean * mean;
  float rstd = rsqrtf(var + 1e-5f);
  out[(size_t)row * 512 + tid] = f2bf((x0 - mean) * rstd * w[tid] + b[tid]);
  out[(size_t)row * 512 + tid + 256] = f2bf((x1 - mean) * rstd * w[tid + 256] + b[tid + 256]);
  if (kpe != nullptr && tid < 32) {
    int p = tid >> 1;
    float xa = px[512 + 2 * p], xb = px[512 + 2 * p + 1];
    float c = cosT[(row << 4) + p], sn = sinT[(row << 4) + p];
    float v = (tid & 1) ? (xa * sn + xb * c) : (xa * c - xb * sn);
    kpe[(row << 5) + tid] = f2bf(v);
  }
}

// ---------------- q_full: copy nope + rope(q_pe), PRE-SCALED by 1/8*log2(e) ----------------
__global__ void build_qfull(const float* __restrict__ q, const float* __restrict__ cosT,
                            const float* __restrict__ sinT, ushort* __restrict__ qf) {
  const float SC = 0.125f * 1.44269504089f;
  int idx = blockIdx.x * blockDim.x + threadIdx.x;
  if (idx >= SLEN * EDIM) return;
  int d = idx & 63;
  int s = idx >> 10;
  const float* base = q + (size_t)(idx - d);
  float v;
  if (d < 32) {
    v = base[d];
  } else {
    int j = d - 32, p = j >> 1;
    float xa = base[32 + 2 * p], xb = base[33 + 2 * p];
    float c = cosT[(s << 4) + p], sn = sinT[(s << 4) + p];
    v = (j & 1) ? (xa * sn + xb * c) : (xa * c - xb * sn);
  }
  qf[idx] = f2bf(v * SC);
}

// ---------------- pack k_full + V^T with k-permutation: vt[h][hd][perm(s)] ----------------
// perm makes each lane's swapped-QK P-values exactly its PV A-fragment (see flash_part).
__global__ __launch_bounds__(256) void pack_kv2(
    const float* __restrict__ kvdec, const ushort* __restrict__ kpe,
    ushort* __restrict__ kf, ushort* __restrict__ vt) {
  __shared__ ushort T[64 * 65];
  const int tid = threadIdx.x;
  const int sb = blockIdx.x, h = blockIdx.y;
  const int s0 = sb * 64;
#pragma unroll 4
  for (int i = 0; i < 16; ++i) {
    int s_loc = i * 4 + (tid >> 6);
    int d = tid & 63;
    const float* base = kvdec + ((size_t)(s0 + s_loc) * 16 + h) * 96;
    T[d * 65 + s_loc] = f2bf(base[32 + d]);
    ushort kval = (d < 32) ? f2bf(base[d]) : kpe[((s0 + s_loc) << 5) + (d - 32)];
    kf[(size_t)(s0 + s_loc) * EDIM + h * 64 + d] = kval;
  }
  __syncthreads();
#pragma unroll 4
  for (int i = 0; i < 16; ++i) {
    int hd = i * 4 + (tid >> 6);
    int s_off = tid & 63;
    // pi(s): s = nf*16 + g*4 + r -> (nf&1)*32 + g*8 + (nf>>1)*4 + r (involution)
    int sp = ((s_off >> 4) & 1) * 32 + ((s_off >> 2) & 3) * 8 + ((s_off >> 5) & 1) * 4 + (s_off & 3);
    vt[(size_t)(h * 64 + hd) * SLEN + s0 + sp] = T[hd * 65 + s_off];
  }
}

// ---------------- flash attention, KV-split partials, swapped-QK ----------------
// Each wave: 16 q-rows, q = lane&15. S^T = mfma(K,Q): lane holds S[q][k=nf*16+g*4+r]
// (g = lane>>4). Lane-local max/sum (+2 shfl_xor), P packed in-register via
// cvt_pk -> PV A-frag directly (V k-axis pre-permuted). No P LDS.
__global__ __launch_bounds__(256, 5) void flash_part(
    const ushort* __restrict__ Qf, const ushort* __restrict__ Kf,
    const ushort* __restrict__ Vt, float* __restrict__ Opart, float* __restrict__ MLpart) {
  __shared__ ushort Klds[64 * 64];
  __shared__ ushort Vlds[64 * 64];
  const int tid = threadIdx.x, lane = tid & 63, wave = tid >> 6;
  const int p = NPAIR - 1 - blockIdx.x;
  const int h = blockIdx.y;
  int qb, ck;
  if (p < 16)      { qb = p;               ck = 0; }
  else if (p < 48) { int j = p - 16; qb = 16 + (j >> 1); ck = j & 1; }
  else if (p < 96) { int j = p - 48; qb = 32 + j / 3;    ck = j - 3 * (j / 3); }
  else             { int j = p - 96; qb = 48 + (j >> 2); ck = j & 3; }
  const int q0 = qb * 64;
  const int t0 = ck * 16;
  const int t1 = min(t0 + 16, qb + 1);

  // Q fragment (B-operand): lane holds Q[q=lane&15][e=(lane>>4)*8+j]
  short8 aq[2];
  {
    const ushort* qrow =
        Qf + (((size_t)(q0 + wave * 16 + (lane & 15)) * 16 + h) << 6) + ((lane >> 4) << 3);
    aq[0] = *(const short8*)qrow;
    aq[1] = *(const short8*)(qrow + 32);
  }
  f32x4 oacc[4];
#pragma unroll
  for (int nf = 0; nf < 4; ++nf) oacc[nf] = (f32x4)0.0f;
  float lacc = 0.0f, mrun = -1e30f;  // per-lane, for q = lane&15

  const int strow = wave * 16 + (lane >> 3);
  const int srcb = ((lane & 7) << 4) ^ (((lane >> 3) & 7) << 4);

  for (int kb = t0; kb < t1; ++kb) {
#pragma unroll
    for (int c = 0; c < 2; ++c) {
      int r = strow + c * 8;
      const ushort* gk = Kf + (((size_t)(kb * 64 + r) * 16 + h) << 6) + (srcb >> 1);
      GLD_LDS16(gk, &Klds[(wave * 16 + c * 8) * 64]);
      const ushort* gv = Vt + (size_t)(h * 64 + r) * SLEN + kb * 64 + (srcb >> 1);
      GLD_LDS16(gv, &Vlds[(wave * 16 + c * 8) * 64]);
    }
    __syncthreads();

    // ---- S^T = K * Q^T : sfr[nf][r] = S[q=lane&15][k = nf*16 + (lane>>4)*4 + r] ----
    f32x4 sfr[4];
#pragma unroll
    for (int nf = 0; nf < 4; ++nf) sfr[nf] = (f32x4)0.0f;
#pragma unroll
    for (int kk = 0; kk < 2; ++kk) {
#pragma unroll
      for (int nf = 0; nf < 4; ++nf) {
        int row = nf * 16 + (lane & 15);
        int cb = (kk * 64 + ((lane >> 4) << 4)) ^ ((row & 7) << 4);
        short8 ak = *(const short8*)((const char*)Klds + row * 128 + cb);
        sfr[nf] = __builtin_amdgcn_mfma_f32_16x16x32_bf16(ak, aq[kk], sfr[nf], 0, 0, 0);
      }
    }
    // ---- causal mask: diagonal tile only ----
    if (kb == qb) {
      const int qloc = wave * 16 + (lane & 15);
      const int kg = (lane >> 4) << 2;
#pragma unroll
      for (int nf = 0; nf < 4; ++nf) {
#pragma unroll
        for (int r = 0; r < 4; ++r)
          if (nf * 16 + kg + r > qloc) sfr[nf][r] = -1e30f;
      }
    }
    // ---- lane-local row max + 2 shfl ----
    float pm = -1e30f;
#pragma unroll
    for (int nf = 0; nf < 4; ++nf)
#pragma unroll
      for (int r = 0; r < 4; ++r) pm = fmaxf(pm, sfr[nf][r]);
    pm = fmaxf(pm, __shfl_xor(pm, 16));
    pm = fmaxf(pm, __shfl_xor(pm, 32));
    // ---- defer-max rescale ----
    if (__any(pm > mrun + 8.0f)) {
      float mnew = fmaxf(mrun, pm);
      float corr = exp2f(mrun - mnew);
      mrun = mnew;
      lacc *= corr;
      const int gbase = lane & 48;
#pragma unroll
      for (int r = 0; r < 4; ++r) {
        float cB = __shfl(corr, gbase + ((lane >> 4) << 2) + r);
#pragma unroll
        for (int nf = 0; nf < 4; ++nf) oacc[nf][r] *= cB;
      }
    }
    // ---- P = exp2(s - m), lane-local sum ----
    float ps = 0.0f;
#pragma unroll
    for (int nf = 0; nf < 4; ++nf)
#pragma unroll
      for (int r = 0; r < 4; ++r) {
        float pv = exp2f(sfr[nf][r] - mrun);
        sfr[nf][r] = pv;
        ps += pv;
      }
    ps += __shfl_xor(ps, 16);
    ps += __shfl_xor(ps, 32);
    lacc += ps;
    // ---- pack P into PV A-frags (zero cross-lane: V k-axis is pre-permuted) ----
    short8 ap[2];
#pragma unroll
    for (int kk = 0; kk < 2; ++kk) {
      union { uint32_t u[4]; short8 s; } pk;
      pk.u[0] = cvt_pk_bf16(sfr[kk][0], sfr[kk][1]);
      pk.u[1] = cvt_pk_bf16(sfr[kk][2], sfr[kk][3]);
      pk.u[2] = cvt_pk_bf16(sfr[kk + 2][0], sfr[kk + 2][1]);
      pk.u[3] = cvt_pk_bf16(sfr[kk + 2][2], sfr[kk + 2][3]);
      ap[kk] = pk.s;
    }
    // ---- O += P V ----
#pragma unroll
    for (int nf = 0; nf < 4; ++nf) {
#pragma unroll
      for (int kk = 0; kk < 2; ++kk) {
        int row = nf * 16 + (lane & 15);
        int cb = (kk * 64 + ((lane >> 4) << 4)) ^ ((row & 7) << 4);
        short8 bv = *(const short8*)((const char*)Vlds + row * 128 + cb);
        oacc[nf] = __builtin_amdgcn_mfma_f32_16x16x32_bf16(ap[kk], bv, oacc[nf], 0, 0, 0);
      }
    }
    __syncthreads();
  }
  // ---- write raw partials: O rows q=(lane>>4)*4+r, cols d=nf*16+lane&15 ----
  const size_t pb = (size_t)h * NPAIR + p;
#pragma unroll
  for (int nf = 0; nf < 4; ++nf) {
#pragma unroll
    for (int r = 0; r < 4; ++r) {
      int row = wave * 16 + ((lane >> 4) << 2) + r;
      int d = nf * 16 + (lane & 15);
      Opart[(pb * 64 + row) * 64 + d] = oacc[nf][r];
    }
  }
  if (lane < 16) {
    MLpart[pb * 128 + wave * 16 + lane] = mrun;
    MLpart[pb * 128 + 64 + wave * 16 + lane] = lacc;
  }
}

// ---------------- combine partials -> attn bf16 [s][h*64+d] ----------------
__global__ __launch_bounds__(256) void flash_combine(
    const float* __restrict__ Opart, const float* __restrict__ MLpart,
    ushort* __restrict__ attn) {
  const int qb = blockIdx.x, h = blockIdx.y;
  const int g = qb >> 4, n = g + 1;
  const int base = (g == 0 ? 0 : g == 1 ? 16 : g == 2 ? 48 : 96) + (qb - (g << 4)) * n;
  __shared__ float mS[4][64], lS[4][64];
  const int tid = threadIdx.x;
  for (int i = tid; i < n * 64; i += 256) {
    int part = i >> 6, row = i & 63;
    size_t pb = (size_t)h * NPAIR + base + part;
    mS[part][row] = MLpart[pb * 128 + row];
    lS[part][row] = MLpart[pb * 128 + 64 + row];
  }
  __syncthreads();
  const int d = tid & 63, rg = tid >> 6;
#pragma unroll 4
  for (int k = 0; k < 16; ++k) {
    int row = rg * 16 + k;
    float M = mS[0][row];
    for (int i = 1; i < n; ++i) M = fmaxf(M, mS[i][row]);
    float L = 0.0f, acc = 0.0f;
    for (int i = 0; i < n; ++i) {
      float w = exp2f(mS[i][row] - M);
      L += lS[i][row] * w;
      acc += Opart[(((size_t)h * NPAIR + base + i) * 64 + row) * 64 + d] * w;
    }
    attn[(size_t)(qb * 64 + row) * EDIM + h * 64 + d] = f2bf(acc / L);
  }
}

// ---------------- launcher ----------------
extern "C" void kernel_launch(void* const* d_in, const int* in_sizes, int n_in,
                              void* d_out, int out_size, void* d_ws, size_t ws_size,
                              hipStream_t stream) {
  const float* x     = (const float*)d_in[0];
  const float* Wqa   = (const float*)d_in[2];
  const float* qa_w  = (const float*)d_in[3];
  const float* qa_b  = (const float*)d_in[4];
  const float* Wqb   = (const float*)d_in[5];
  const float* Wkva  = (const float*)d_in[6];
  const float* kva_w = (const float*)d_in[7];
  const float* kva_b = (const float*)d_in[8];
  const float* Wkvb  = (const float*)d_in[9];
  const float* Wo    = (const float*)d_in[10];
  float* out = (float*)d_out;

  char* ws = (char*)d_ws;
  size_t off = 0;
  auto alloc = [&](size_t bytes) {
    char* p = ws + off;
    off += (bytes + 255) & ~(size_t)255;
    return p;
  };
  ushort* xb      = (ushort*)alloc((size_t)SLEN * EDIM * 2);
  ushort* wqkva_b = (ushort*)alloc((size_t)1056 * 1024 * 2);
  ushort* wqb_b   = (ushort*)alloc((size_t)1024 * 512 * 2);
  ushort* wkvb_b  = (ushort*)alloc((size_t)1536 * 512 * 2);
  ushort* wo_b    = (ushort*)alloc((size_t)1024 * 1024 * 2);
  float*  cosT    = (float*)alloc((size_t)SLEN * 16 * 4);
  float*  sinT    = (float*)alloc((size_t)SLEN * 16 * 4);
  ushort* qc_b    = (ushort*)alloc((size_t)SLEN * 512 * 2);
  ushort* qf_b    = (ushort*)alloc((size_t)SLEN * EDIM * 2);
  ushort* ckv_b   = (ushort*)alloc((size_t)SLEN * 512 * 2);
  ushort* kpe_b   = (ushort*)alloc((size_t)SLEN * 32 * 2);
  ushort* kf_b    = (ushort*)alloc((size_t)SLEN * EDIM * 2);
  ushort* vt_b    = (ushort*)alloc((size_t)SLEN * EDIM * 2);
  ushort* attn_b  = (ushort*)alloc((size_t)SLEN * EDIM * 2);
  size_t interm = (size_t)SLEN * 1536 * 4;
  size_t parts  = (size_t)NH * NPAIR * 64 * 64 * 4 + (size_t)NH * NPAIR * 128 * 4;
  char* R = alloc(interm > parts ? interm : parts);
  float* qakv_f  = (float*)R;
  float* q_f     = (float*)R;
  float* kvdec_f = (float*)R;
  float* Opart   = (float*)R;
  float* MLpart  = (float*)(R + (size_t)NH * NPAIR * 64 * 64 * 4);

  auto cast = [&](const float* src, ushort* dst, int n) {
    cast_bf16<<<dim3((n / 4 + 255) / 256), 256, 0, stream>>>((const float4*)src, dst, n / 4);
  };
  cast(x, xb, SLEN * EDIM);
  cast(Wqa, wqkva_b, 512 * 1024);
  cast(Wkva, wqkva_b + (size_t)512 * 1024, 544 * 1024);
  cast(Wqb, wqb_b, 1024 * 512);
  cast(Wkvb, wkvb_b, 1536 * 512);
  cast(Wo, wo_b, 1024 * 1024);
  rope_table<<<dim3((SLEN * 16 + 255) / 256), 256, 0, stream>>>(cosT, sinT);

  gemm_bt<<<dim3(64, 9), 256, 0, stream>>>(xb, wqkva_b, qakv_f, SLEN, 1056, 1024);
  ln_kernel<<<dim3(SLEN), 256, 0, stream>>>(qakv_f, 1056, qa_w, qa_b, qc_b, nullptr, nullptr, nullptr);
  ln_kernel<<<dim3(SLEN), 256, 0, stream>>>(qakv_f + 512, 1056, kva_w, kva_b, ckv_b, cosT, sinT, kpe_b);
  gemm_bt<<<dim3(64, 8), 256, 0, stream>>>(qc_b, wqb_b, q_f, SLEN, 1024, 512);
  build_qfull<<<dim3(SLEN * EDIM / 256), 256, 0, stream>>>(q_f, cosT, sinT, qf_b);
  gemm_bt<<<dim3(64, 12), 256, 0, stream>>>(ckv_b, wkvb_b, kvdec_f, SLEN, 1536, 512);
  pack_kv2<<<dim3(64, 16), 256, 0, stream>>>(kvdec_f, kpe_b, kf_b, vt_b);

  flash_part<<<dim3(NPAIR, 16), 256, 0, stream>>>(qf_b, kf_b, vt_b, Opart, MLpart);
  flash_combine<<<dim3(64, 16), 256, 0, stream>>>(Opart, MLpart, attn_b);
  gemm_bt<<<dim3(64, 8), 256, 0, stream>>>(attn_b, wo_b, out, SLEN, 1024, 1024);

  (void)in_sizes; (void)n_in; (void)out_size; (void)ws_size;
}

// Round 6
// 215.801 us; speedup vs baseline: 2.0859x; 1.0229x over previous
//
#include <hip/hip_runtime.h>
#include <hip/hip_bf16.h>
#include <stdint.h>

// ---------------- MLA decoder self-attention, bf16-MFMA pipeline ----------------
// S=4096 E=1024 H=16 HD=64 ROPE=32 NOPE=32 QR=512 KVR=512, causal.
// R5: flash 8 blocks/CU; bf16 intermediates everywhere (GEMM bf16 epilogue,
// bf16 Opart partials); dual-GEMM launch (wqb+wkvb); single fused cast kernel.

#define SLEN 4096
#define EDIM 1024
#define NH   16
#define NPAIR 160   // sum over qb of floor(qb/16)+1

typedef __attribute__((ext_vector_type(8))) short short8;
typedef __attribute__((ext_vector_type(4))) float f32x4;

__device__ __forceinline__ ushort f2bf(float f) {
  __hip_bfloat16 h = __float2bfloat16(f);
  ushort u; __builtin_memcpy(&u, &h, 2); return u;
}
__device__ __forceinline__ float bf2f(ushort u) {
  uint32_t x = (uint32_t)u << 16;
  float f; __builtin_memcpy(&f, &x, 4); return f;
}
__device__ __forceinline__ uint32_t cvt_pk_bf16(float lo, float hi) {
  uint32_t r;
  asm("v_cvt_pk_bf16_f32 %0, %1, %2" : "=v"(r) : "v"(lo), "v"(hi));
  return r;
}

#define GLD_LDS16(g, l) __builtin_amdgcn_global_load_lds(                      \
    (const __attribute__((address_space(1))) uint32_t*)(g),                    \
    (__attribute__((address_space(3))) uint32_t*)(l), 16, 0, 0)

// ---------------- fused cast: 6 tensors f32 -> bf16, one launch ----------------
struct CastSeg { const float4* src; ushort* dst; int n4; };
struct CastArgs { CastSeg seg[6]; int total4; };
__global__ void cast_all(CastArgs a) {
  int i = blockIdx.x * blockDim.x + threadIdx.x;
  int stride = gridDim.x * blockDim.x;
  for (; i < a.total4; i += stride) {
    int idx = i, s = 0;
    while (idx >= a.seg[s].n4) { idx -= a.seg[s].n4; ++s; }
    float4 v = a.seg[s].src[idx];
    ushort4 o;
    o.x = f2bf(v.x); o.y = f2bf(v.y); o.z = f2bf(v.z); o.w = f2bf(v.w);
    *(ushort4*)(a.seg[s].dst + (size_t)idx * 4) = o;
  }
}

// ---------------- rope tables: cos/sin[s][16] ----------------
__global__ void rope_table(float* __restrict__ cosT, float* __restrict__ sinT) {
  int idx = blockIdx.x * blockDim.x + threadIdx.x;
  if (idx >= SLEN * 16) return;
  int s = idx >> 4, i = idx & 15;
  float inv = expf(-((float)(2 * i) / 32.0f) * logf(10000.0f));
  float ang = (float)s * inv;
  cosT[idx] = cosf(ang);
  sinT[idx] = sinf(ang);
}

// ---------------- GEMM body: C[M,N] = A[M,K]*B[N,K]^T, bf16 in, f32/bf16 out ----------------
template <typename CT>
__device__ __forceinline__ void gemm_body(
    ushort* As, ushort* Bs,
    const ushort* __restrict__ A, const ushort* __restrict__ B, CT* __restrict__ C,
    int M, int N, int K, int bx, int by) {
  const int tid = threadIdx.x;
  const int lane = tid & 63, wave = tid >> 6;
  const int bm = bx * 64, bn = by * 128;
  const int wm = (wave >> 1) * 32, wn = (wave & 1) * 64;

  f32x4 acc[2][4];
#pragma unroll
  for (int m = 0; m < 2; ++m)
#pragma unroll
    for (int n = 0; n < 4; ++n) acc[m][n] = (f32x4)0.0f;

  const int srow = lane >> 3;
  const int scb = (lane & 7) << 4;
  const int srcb = scb ^ ((srow & 7) << 4);

  for (int k0 = 0; k0 < K; k0 += 64) {
    __syncthreads();
#pragma unroll
    for (int c = 0; c < 2; ++c) {
      int r = wave * 16 + c * 8 + srow;
      const ushort* ga = A + (size_t)(bm + r) * K + k0 + (srcb >> 1);
      GLD_LDS16(ga, As + (wave * 16 + c * 8) * 64);
    }
#pragma unroll
    for (int c = 0; c < 4; ++c) {
      int r = wave * 32 + c * 8 + srow;
      int rb = bn + r; if (rb >= N) rb = N - 1;
      const ushort* gb = B + (size_t)rb * K + k0 + (srcb >> 1);
      GLD_LDS16(gb, Bs + (wave * 32 + c * 8) * 64);
    }
    __syncthreads();
#pragma unroll
    for (int kk = 0; kk < 2; ++kk) {
      short8 af[2], bf[4];
#pragma unroll
      for (int m = 0; m < 2; ++m) {
        int row = wm + m * 16 + (lane & 15);
        int cb = (kk * 64 + ((lane >> 4) << 4)) ^ ((row & 7) << 4);
        af[m] = *(const short8*)((const char*)As + row * 128 + cb);
      }
#pragma unroll
      for (int n = 0; n < 4; ++n) {
        int row = wn + n * 16 + (lane & 15);
        int cb = (kk * 64 + ((lane >> 4) << 4)) ^ ((row & 7) << 4);
        bf[n] = *(const short8*)((const char*)Bs + row * 128 + cb);
      }
#pragma unroll
      for (int m = 0; m < 2; ++m)
#pragma unroll
        for (int n = 0; n < 4; ++n)
          acc[m][n] = __builtin_amdgcn_mfma_f32_16x16x32_bf16(af[m], bf[n], acc[m][n], 0, 0, 0);
    }
  }
#pragma unroll
  for (int m = 0; m < 2; ++m) {
    int gm = bm + wm + m * 16 + ((lane >> 4) << 2);
#pragma unroll
    for (int n = 0; n < 4; ++n) {
      int gn = bn + wn + n * 16 + (lane & 15);
      if (gn < N) {
#pragma unroll
        for (int r = 0; r < 4; ++r) {
          float v = acc[m][n][r];
          if constexpr (__is_same(CT, ushort))
            C[(size_t)(gm + r) * N + gn] = f2bf(v);
          else
            C[(size_t)(gm + r) * N + gn] = v;
        }
      }
    }
  }
}

__global__ __launch_bounds__(256, 4) void gemm_f32k(
    const ushort* __restrict__ A, const ushort* __restrict__ B, float* __restrict__ C,
    int M, int N, int K) {
  __shared__ ushort As[64 * 64];
  __shared__ ushort Bs[128 * 64];
  gemm_body<float>(As, Bs, A, B, C, M, N, K, blockIdx.x, blockIdx.y);
}
__global__ __launch_bounds__(256, 4) void gemm_bf16k(
    const ushort* __restrict__ A, const ushort* __restrict__ B, ushort* __restrict__ C,
    int M, int N, int K) {
  __shared__ ushort As[64 * 64];
  __shared__ ushort Bs[128 * 64];
  gemm_body<ushort>(As, Bs, A, B, C, M, N, K, blockIdx.x, blockIdx.y);
}
// wqb (N=1024, y<8) and wkvb (N=1536, y>=8) in one launch: 64x20 = 1280 blocks
__global__ __launch_bounds__(256, 4) void gemm_dual(
    const ushort* __restrict__ Aq, const ushort* __restrict__ Bq, ushort* __restrict__ Cq,
    const ushort* __restrict__ Ak, const ushort* __restrict__ Bk, ushort* __restrict__ Ck) {
  __shared__ ushort As[64 * 64];
  __shared__ ushort Bs[128 * 64];
  if (blockIdx.y < 8)
    gemm_body<ushort>(As, Bs, Aq, Bq, Cq, SLEN, 1024, 512, blockIdx.x, blockIdx.y);
  else
    gemm_body<ushort>(As, Bs, Ak, Bk, Ck, SLEN, 1536, 512, blockIdx.x, blockIdx.y - 8);
}

// ---------------- LayerNorm over 512 cols (bf16 in, +optional k_pe rope) ----------------
__global__ __launch_bounds__(256) void ln_kernel(
    const ushort* __restrict__ in, int ldin, const float* __restrict__ w,
    const float* __restrict__ b, ushort* __restrict__ out,
    const float* __restrict__ cosT, const float* __restrict__ sinT,
    ushort* __restrict__ kpe) {
  int row = blockIdx.x, tid = threadIdx.x;
  const ushort* px = in + (size_t)row * ldin;
  float x0 = bf2f(px[tid]), x1 = bf2f(px[tid + 256]);
  float s = x0 + x1, sq = x0 * x0 + x1 * x1;
#pragma unroll
  for (int off = 32; off; off >>= 1) {
    s += __shfl_down(s, off);
    sq += __shfl_down(sq, off);
  }
  __shared__ float redS[4], redQ[4];
  int wave = tid >> 6, lane = tid & 63;
  if (lane == 0) { redS[wave] = s; redQ[wave] = sq; }
  __syncthreads();
  float st = redS[0] + redS[1] + redS[2] + redS[3];
  float sqt = redQ[0] + redQ[1] + redQ[2] + redQ[3];
  float mean = st * (1.0f / 512.0f);
  float var = sqt * (1.0f / 512.0f) - mean * mean;
  float rstd = rsqrtf(var + 1e-5f);
  out[(size_t)row * 512 + tid] = f2bf((x0 - mean) * rstd * w[tid] + b[tid]);
  out[(size_t)row * 512 + tid + 256] = f2bf((x1 - mean) * rstd * w[tid + 256] + b[tid + 256]);
  if (kpe != nullptr && tid < 32) {
    int p = tid >> 1;
    float xa = bf2f(px[512 + 2 * p]), xb = bf2f(px[512 + 2 * p + 1]);
    float c = cosT[(row << 4) + p], sn = sinT[(row << 4) + p];
    float v = (tid & 1) ? (xa * sn + xb * c) : (xa * c - xb * sn);
    kpe[(row << 5) + tid] = f2bf(v);
  }
}

// ---------------- q_full: copy nope + rope(q_pe), PRE-SCALED by 1/8*log2(e) ----------------
__global__ void build_qfull(const ushort* __restrict__ q, const float* __restrict__ cosT,
                            const float* __restrict__ sinT, ushort* __restrict__ qf) {
  const float SC = 0.125f * 1.44269504089f;
  int idx = blockIdx.x * blockDim.x + threadIdx.x;
  if (idx >= SLEN * EDIM) return;
  int d = idx & 63;
  int s = idx >> 10;
  const ushort* base = q + (size_t)(idx - d);
  float v;
  if (d < 32) {
    v = bf2f(base[d]);
  } else {
    int j = d - 32, p = j >> 1;
    float xa = bf2f(base[32 + 2 * p]), xb = bf2f(base[33 + 2 * p]);
    float c = cosT[(s << 4) + p], sn = sinT[(s << 4) + p];
    v = (j & 1) ? (xa * sn + xb * c) : (xa * c - xb * sn);
  }
  qf[idx] = f2bf(v * SC);
}

// ---------------- pack k_full + V^T with k-permutation: vt[h][hd][perm(s)] ----------------
__global__ __launch_bounds__(256) void pack_kv2(
    const ushort* __restrict__ kvdec, const ushort* __restrict__ kpe,
    ushort* __restrict__ kf, ushort* __restrict__ vt) {
  __shared__ ushort T[64 * 65];
  const int tid = threadIdx.x;
  const int sb = blockIdx.x, h = blockIdx.y;
  const int s0 = sb * 64;
#pragma unroll 4
  for (int i = 0; i < 16; ++i) {
    int s_loc = i * 4 + (tid >> 6);
    int d = tid & 63;
    const ushort* base = kvdec + ((size_t)(s0 + s_loc) * 16 + h) * 96;
    T[d * 65 + s_loc] = base[32 + d];
    ushort kval = (d < 32) ? base[d] : kpe[((s0 + s_loc) << 5) + (d - 32)];
    kf[(size_t)(s0 + s_loc) * EDIM + h * 64 + d] = kval;
  }
  __syncthreads();
#pragma unroll 4
  for (int i = 0; i < 16; ++i) {
    int hd = i * 4 + (tid >> 6);
    int s_off = tid & 63;
    // pi(s): s = nf*16 + g*4 + r -> (nf&1)*32 + g*8 + (nf>>1)*4 + r (involution)
    int sp = ((s_off >> 4) & 1) * 32 + ((s_off >> 2) & 3) * 8 + ((s_off >> 5) & 1) * 4 + (s_off & 3);
    vt[(size_t)(h * 64 + hd) * SLEN + s0 + sp] = T[hd * 65 + s_off];
  }
}

// ---------------- flash attention, KV-split partials, swapped-QK ----------------
__global__ __launch_bounds__(256, 8) void flash_part(
    const ushort* __restrict__ Qf, const ushort* __restrict__ Kf,
    const ushort* __restrict__ Vt, ushort* __restrict__ Opart, float* __restrict__ MLpart) {
  __shared__ ushort Klds[64 * 64];
  __shared__ ushort Vlds[64 * 64];
  const int tid = threadIdx.x, lane = tid & 63, wave = tid >> 6;
  const int p = NPAIR - 1 - blockIdx.x;
  const int h = blockIdx.y;
  int qb, ck;
  if (p < 16)      { qb = p;               ck = 0; }
  else if (p < 48) { int j = p - 16; qb = 16 + (j >> 1); ck = j & 1; }
  else if (p < 96) { int j = p - 48; qb = 32 + j / 3;    ck = j - 3 * (j / 3); }
  else             { int j = p - 96; qb = 48 + (j >> 2); ck = j & 3; }
  const int q0 = qb * 64;
  const int t0 = ck * 16;
  const int t1 = min(t0 + 16, qb + 1);

  short8 aq[2];
  {
    const ushort* qrow =
        Qf + (((size_t)(q0 + wave * 16 + (lane & 15)) * 16 + h) << 6) + ((lane >> 4) << 3);
    aq[0] = *(const short8*)qrow;
    aq[1] = *(const short8*)(qrow + 32);
  }
  f32x4 oacc[4];
#pragma unroll
  for (int nf = 0; nf < 4; ++nf) oacc[nf] = (f32x4)0.0f;
  float lacc = 0.0f, mrun = -1e30f;

  const int strow = wave * 16 + (lane >> 3);
  const int srcb = ((lane & 7) << 4) ^ (((lane >> 3) & 7) << 4);

  for (int kb = t0; kb < t1; ++kb) {
#pragma unroll
    for (int c = 0; c < 2; ++c) {
      int r = strow + c * 8;
      const ushort* gk = Kf + (((size_t)(kb * 64 + r) * 16 + h) << 6) + (srcb >> 1);
      GLD_LDS16(gk, &Klds[(wave * 16 + c * 8) * 64]);
      const ushort* gv = Vt + (size_t)(h * 64 + r) * SLEN + kb * 64 + (srcb >> 1);
      GLD_LDS16(gv, &Vlds[(wave * 16 + c * 8) * 64]);
    }
    __syncthreads();

    // ---- S^T = K * Q^T : sfr[nf][r] = S[q=lane&15][k = nf*16 + (lane>>4)*4 + r] ----
    f32x4 sfr[4];
#pragma unroll
    for (int nf = 0; nf < 4; ++nf) sfr[nf] = (f32x4)0.0f;
#pragma unroll
    for (int kk = 0; kk < 2; ++kk) {
#pragma unroll
      for (int nf = 0; nf < 4; ++nf) {
        int row = nf * 16 + (lane & 15);
        int cb = (kk * 64 + ((lane >> 4) << 4)) ^ ((row & 7) << 4);
        short8 ak = *(const short8*)((const char*)Klds + row * 128 + cb);
        sfr[nf] = __builtin_amdgcn_mfma_f32_16x16x32_bf16(ak, aq[kk], sfr[nf], 0, 0, 0);
      }
    }
    if (kb == qb) {
      const int qloc = wave * 16 + (lane & 15);
      const int kg = (lane >> 4) << 2;
#pragma unroll
      for (int nf = 0; nf < 4; ++nf) {
#pragma unroll
        for (int r = 0; r < 4; ++r)
          if (nf * 16 + kg + r > qloc) sfr[nf][r] = -1e30f;
      }
    }
    float pm = -1e30f;
#pragma unroll
    for (int nf = 0; nf < 4; ++nf)
#pragma unroll
      for (int r = 0; r < 4; ++r) pm = fmaxf(pm, sfr[nf][r]);
    pm = fmaxf(pm, __shfl_xor(pm, 16));
    pm = fmaxf(pm, __shfl_xor(pm, 32));
    if (__any(pm > mrun + 8.0f)) {
      float mnew = fmaxf(mrun, pm);
      float corr = exp2f(mrun - mnew);
      mrun = mnew;
      lacc *= corr;
      const int gbase = lane & 48;
#pragma unroll
      for (int r = 0; r < 4; ++r) {
        float cB = __shfl(corr, gbase + ((lane >> 4) << 2) + r);
#pragma unroll
        for (int nf = 0; nf < 4; ++nf) oacc[nf][r] *= cB;
      }
    }
    float ps = 0.0f;
#pragma unroll
    for (int nf = 0; nf < 4; ++nf)
#pragma unroll
      for (int r = 0; r < 4; ++r) {
        float pv = exp2f(sfr[nf][r] - mrun);
        sfr[nf][r] = pv;
        ps += pv;
      }
    ps += __shfl_xor(ps, 16);
    ps += __shfl_xor(ps, 32);
    lacc += ps;
    short8 ap[2];
#pragma unroll
    for (int kk = 0; kk < 2; ++kk) {
      union { uint32_t u[4]; short8 s; } pk;
      pk.u[0] = cvt_pk_bf16(sfr[kk][0], sfr[kk][1]);
      pk.u[1] = cvt_pk_bf16(sfr[kk][2], sfr[kk][3]);
      pk.u[2] = cvt_pk_bf16(sfr[kk + 2][0], sfr[kk + 2][1]);
      pk.u[3] = cvt_pk_bf16(sfr[kk + 2][2], sfr[kk + 2][3]);
      ap[kk] = pk.s;
    }
#pragma unroll
    for (int nf = 0; nf < 4; ++nf) {
#pragma unroll
      for (int kk = 0; kk < 2; ++kk) {
        int row = nf * 16 + (lane & 15);
        int cb = (kk * 64 + ((lane >> 4) << 4)) ^ ((row & 7) << 4);
        short8 bv = *(const short8*)((const char*)Vlds + row * 128 + cb);
        oacc[nf] = __builtin_amdgcn_mfma_f32_16x16x32_bf16(ap[kk], bv, oacc[nf], 0, 0, 0);
      }
    }
    __syncthreads();
  }
  // ---- write bf16 partials ----
  const size_t pb = (size_t)h * NPAIR + p;
#pragma unroll
  for (int nf = 0; nf < 4; ++nf) {
#pragma unroll
    for (int r = 0; r < 4; ++r) {
      int row = wave * 16 + ((lane >> 4) << 2) + r;
      int d = nf * 16 + (lane & 15);
      Opart[(pb * 64 + row) * 64 + d] = f2bf(oacc[nf][r]);
    }
  }
  if (lane < 16) {
    MLpart[pb * 128 + wave * 16 + lane] = mrun;
    MLpart[pb * 128 + 64 + wave * 16 + lane] = lacc;
  }
}

// ---------------- combine partials -> attn bf16 [s][h*64+d] ----------------
__global__ __launch_bounds__(256) void flash_combine(
    const ushort* __restrict__ Opart, const float* __restrict__ MLpart,
    ushort* __restrict__ attn) {
  const int qb = blockIdx.x, h = blockIdx.y;
  const int g = qb >> 4, n = g + 1;
  const int base = (g == 0 ? 0 : g == 1 ? 16 : g == 2 ? 48 : 96) + (qb - (g << 4)) * n;
  __shared__ float mS[4][64], lS[4][64];
  const int tid = threadIdx.x;
  for (int i = tid; i < n * 64; i += 256) {
    int part = i >> 6, row = i & 63;
    size_t pb = (size_t)h * NPAIR + base + part;
    mS[part][row] = MLpart[pb * 128 + row];
    lS[part][row] = MLpart[pb * 128 + 64 + row];
  }
  __syncthreads();
  const int d = tid & 63, rg = tid >> 6;
#pragma unroll 4
  for (int k = 0; k < 16; ++k) {
    int row = rg * 16 + k;
    float M = mS[0][row];
    for (int i = 1; i < n; ++i) M = fmaxf(M, mS[i][row]);
    float L = 0.0f, acc = 0.0f;
    for (int i = 0; i < n; ++i) {
      float w = exp2f(mS[i][row] - M);
      L += lS[i][row] * w;
      acc += bf2f(Opart[(((size_t)h * NPAIR + base + i) * 64 + row) * 64 + d]) * w;
    }
    attn[(size_t)(qb * 64 + row) * EDIM + h * 64 + d] = f2bf(acc / L);
  }
}

// ---------------- launcher ----------------
extern "C" void kernel_launch(void* const* d_in, const int* in_sizes, int n_in,
                              void* d_out, int out_size, void* d_ws, size_t ws_size,
                              hipStream_t stream) {
  const float* x     = (const float*)d_in[0];
  const float* Wqa   = (const float*)d_in[2];
  const float* qa_w  = (const float*)d_in[3];
  const float* qa_b  = (const float*)d_in[4];
  const float* Wqb   = (const float*)d_in[5];
  const float* Wkva  = (const float*)d_in[6];
  const float* kva_w = (const float*)d_in[7];
  const float* kva_b = (const float*)d_in[8];
  const float* Wkvb  = (const float*)d_in[9];
  const float* Wo    = (const float*)d_in[10];
  float* out = (float*)d_out;

  char* ws = (char*)d_ws;
  size_t off = 0;
  auto alloc = [&](size_t bytes) {
    char* p = ws + off;
    off += (bytes + 255) & ~(size_t)255;
    return p;
  };
  ushort* xb      = (ushort*)alloc((size_t)SLEN * EDIM * 2);
  ushort* wqkva_b = (ushort*)alloc((size_t)1056 * 1024 * 2);
  ushort* wqb_b   = (ushort*)alloc((size_t)1024 * 512 * 2);
  ushort* wkvb_b  = (ushort*)alloc((size_t)1536 * 512 * 2);
  ushort* wo_b    = (ushort*)alloc((size_t)1024 * 1024 * 2);
  float*  cosT    = (float*)alloc((size_t)SLEN * 16 * 4);
  float*  sinT    = (float*)alloc((size_t)SLEN * 16 * 4);
  ushort* qc_b    = (ushort*)alloc((size_t)SLEN * 512 * 2);
  ushort* qf_b    = (ushort*)alloc((size_t)SLEN * EDIM * 2);
  ushort* ckv_b   = (ushort*)alloc((size_t)SLEN * 512 * 2);
  ushort* kpe_b   = (ushort*)alloc((size_t)SLEN * 32 * 2);
  ushort* kf_b    = (ushort*)alloc((size_t)SLEN * EDIM * 2);
  ushort* vt_b    = (ushort*)alloc((size_t)SLEN * EDIM * 2);
  ushort* attn_b  = (ushort*)alloc((size_t)SLEN * EDIM * 2);
  ushort* qakv_bf = (ushort*)alloc((size_t)SLEN * 1056 * 2);   // 8.65 MB
  float*  MLpart  = (float*)alloc((size_t)NH * NPAIR * 128 * 4);
  // q_bf (8.39MB) + kvdec_bf (12.58MB) alias Opart (20.97MB): both dead pre-flash
  char* RB = alloc((size_t)SLEN * 1024 * 2 + (size_t)SLEN * 1536 * 2);
  ushort* q_bf     = (ushort*)RB;
  ushort* kvdec_bf = (ushort*)(RB + (size_t)SLEN * 1024 * 2);
  ushort* Opart    = (ushort*)RB;  // NH*NPAIR*64*64*2 = 20.97 MB exactly

  // ---- fused casts ----
  CastArgs ca;
  ca.seg[0] = { (const float4*)x,    xb,                               SLEN * EDIM / 4 };
  ca.seg[1] = { (const float4*)Wqa,  wqkva_b,                          512 * 1024 / 4 };
  ca.seg[2] = { (const float4*)Wkva, wqkva_b + (size_t)512 * 1024,     544 * 1024 / 4 };
  ca.seg[3] = { (const float4*)Wqb,  wqb_b,                            1024 * 512 / 4 };
  ca.seg[4] = { (const float4*)Wkvb, wkvb_b,                           1536 * 512 / 4 };
  ca.seg[5] = { (const float4*)Wo,   wo_b,                             1024 * 1024 / 4 };
  ca.total4 = ca.seg[0].n4 + ca.seg[1].n4 + ca.seg[2].n4 + ca.seg[3].n4 + ca.seg[4].n4 + ca.seg[5].n4;
  cast_all<<<dim3(2048), 256, 0, stream>>>(ca);
  rope_table<<<dim3((SLEN * 16 + 255) / 256), 256, 0, stream>>>(cosT, sinT);

  // merged qa+kva projection (bf16 out)
  gemm_bf16k<<<dim3(64, 9), 256, 0, stream>>>(xb, wqkva_b, qakv_bf, SLEN, 1056, 1024);
  ln_kernel<<<dim3(SLEN), 256, 0, stream>>>(qakv_bf, 1056, qa_w, qa_b, qc_b, nullptr, nullptr, nullptr);
  ln_kernel<<<dim3(SLEN), 256, 0, stream>>>(qakv_bf + 512, 1056, kva_w, kva_b, ckv_b, cosT, sinT, kpe_b);
  // wqb + wkvb in one launch (bf16 out)
  gemm_dual<<<dim3(64, 20), 256, 0, stream>>>(qc_b, wqb_b, q_bf, ckv_b, wkvb_b, kvdec_bf);
  build_qfull<<<dim3(SLEN * EDIM / 256), 256, 0, stream>>>(q_bf, cosT, sinT, qf_b);
  pack_kv2<<<dim3(64, 16), 256, 0, stream>>>(kvdec_bf, kpe_b, kf_b, vt_b);

  flash_part<<<dim3(NPAIR, 16), 256, 0, stream>>>(qf_b, kf_b, vt_b, Opart, MLpart);
  flash_combine<<<dim3(64, 16), 256, 0, stream>>>(Opart, MLpart, attn_b);
  gemm_f32k<<<dim3(64, 8), 256, 0, stream>>>(attn_b, wo_b, out, SLEN, 1024, 1024);

  (void)in_sizes; (void)n_in; (void)out_size; (void)ws_size;
}

// Round 7
// 195.089 us; speedup vs baseline: 2.3074x; 1.1062x over previous
//
#include <hip/hip_runtime.h>
#include <hip/hip_bf16.h>
#include <stdint.h>

// ---------------- MLA decoder self-attention, bf16-MFMA pipeline ----------------
// S=4096 E=1024 H=16 HD=64 ROPE=32 NOPE=32 QR=512 KVR=512, causal.
// R6: flash back to (256,5) [8-waves/EU caused VGPR-32 spills]; GEMMs 2-phase
// double-buffered (T3-minimum: prefetch issued before compute, 1 barrier/K-step).

#define SLEN 4096
#define EDIM 1024
#define NH   16
#define NPAIR 160   // sum over qb of floor(qb/16)+1

typedef __attribute__((ext_vector_type(8))) short short8;
typedef __attribute__((ext_vector_type(4))) float f32x4;

__device__ __forceinline__ ushort f2bf(float f) {
  __hip_bfloat16 h = __float2bfloat16(f);
  ushort u; __builtin_memcpy(&u, &h, 2); return u;
}
__device__ __forceinline__ float bf2f(ushort u) {
  uint32_t x = (uint32_t)u << 16;
  float f; __builtin_memcpy(&f, &x, 4); return f;
}
__device__ __forceinline__ uint32_t cvt_pk_bf16(float lo, float hi) {
  uint32_t r;
  asm("v_cvt_pk_bf16_f32 %0, %1, %2" : "=v"(r) : "v"(lo), "v"(hi));
  return r;
}

#define GLD_LDS16(g, l) __builtin_amdgcn_global_load_lds(                      \
    (const __attribute__((address_space(1))) uint32_t*)(g),                    \
    (__attribute__((address_space(3))) uint32_t*)(l), 16, 0, 0)

// ---------------- fused cast: 6 tensors f32 -> bf16, one launch ----------------
struct CastSeg { const float4* src; ushort* dst; int n4; };
struct CastArgs { CastSeg seg[6]; int total4; };
__global__ void cast_all(CastArgs a) {
  int i = blockIdx.x * blockDim.x + threadIdx.x;
  int stride = gridDim.x * blockDim.x;
  for (; i < a.total4; i += stride) {
    int idx = i, s = 0;
    while (idx >= a.seg[s].n4) { idx -= a.seg[s].n4; ++s; }
    float4 v = a.seg[s].src[idx];
    ushort4 o;
    o.x = f2bf(v.x); o.y = f2bf(v.y); o.z = f2bf(v.z); o.w = f2bf(v.w);
    *(ushort4*)(a.seg[s].dst + (size_t)idx * 4) = o;
  }
}

// ---------------- rope tables: cos/sin[s][16] ----------------
__global__ void rope_table(float* __restrict__ cosT, float* __restrict__ sinT) {
  int idx = blockIdx.x * blockDim.x + threadIdx.x;
  if (idx >= SLEN * 16) return;
  int s = idx >> 4, i = idx & 15;
  float inv = expf(-((float)(2 * i) / 32.0f) * logf(10000.0f));
  float ang = (float)s * inv;
  cosT[idx] = cosf(ang);
  sinT[idx] = sinf(ang);
}

// ---------------- GEMM body: C = A*B^T, 64x128 tile, 2-phase double-buffered ----------------
// As: [2][64*64] ushort, Bs: [2][128*64] ushort (48 KB total LDS).
template <typename CT>
__device__ __forceinline__ void gemm_body(
    ushort* As, ushort* Bs,
    const ushort* __restrict__ A, const ushort* __restrict__ B, CT* __restrict__ C,
    int M, int N, int K, int bx, int by) {
  const int tid = threadIdx.x;
  const int lane = tid & 63, wave = tid >> 6;
  const int bm = bx * 64, bn = by * 128;
  const int wm = (wave >> 1) * 32, wn = (wave & 1) * 64;

  f32x4 acc[2][4];
#pragma unroll
  for (int m = 0; m < 2; ++m)
#pragma unroll
    for (int n = 0; n < 4; ++n) acc[m][n] = (f32x4)0.0f;

  const int srow = lane >> 3;
  const int scb = (lane & 7) << 4;
  const int srcb = scb ^ ((srow & 7) << 4);

  auto stage = [&](int k0, int buf) {
#pragma unroll
    for (int c = 0; c < 2; ++c) {
      int r = wave * 16 + c * 8 + srow;
      const ushort* ga = A + (size_t)(bm + r) * K + k0 + (srcb >> 1);
      GLD_LDS16(ga, As + buf * 4096 + (wave * 16 + c * 8) * 64);
    }
#pragma unroll
    for (int c = 0; c < 4; ++c) {
      int r = wave * 32 + c * 8 + srow;
      int rb = bn + r; if (rb >= N) rb = N - 1;
      const ushort* gb = B + (size_t)rb * K + k0 + (srcb >> 1);
      GLD_LDS16(gb, Bs + buf * 8192 + (wave * 32 + c * 8) * 64);
    }
  };

  stage(0, 0);
  __syncthreads();  // vmcnt drained: buf0 ready
  int cur = 0;
  for (int k0 = 0; k0 < K; k0 += 64) {
    if (k0 + 64 < K) stage(k0 + 64, cur ^ 1);  // prefetch under compute
    const char* Ab = (const char*)(As + cur * 4096);
    const char* Bb = (const char*)(Bs + cur * 8192);
#pragma unroll
    for (int kk = 0; kk < 2; ++kk) {
      short8 af[2], bf[4];
#pragma unroll
      for (int m = 0; m < 2; ++m) {
        int row = wm + m * 16 + (lane & 15);
        int cb = (kk * 64 + ((lane >> 4) << 4)) ^ ((row & 7) << 4);
        af[m] = *(const short8*)(Ab + row * 128 + cb);
      }
#pragma unroll
      for (int n = 0; n < 4; ++n) {
        int row = wn + n * 16 + (lane & 15);
        int cb = (kk * 64 + ((lane >> 4) << 4)) ^ ((row & 7) << 4);
        bf[n] = *(const short8*)(Bb + row * 128 + cb);
      }
#pragma unroll
      for (int m = 0; m < 2; ++m)
#pragma unroll
        for (int n = 0; n < 4; ++n)
          acc[m][n] = __builtin_amdgcn_mfma_f32_16x16x32_bf16(af[m], bf[n], acc[m][n], 0, 0, 0);
    }
    __syncthreads();  // drains vmcnt (next buf staged) + lgkm (cur reads done)
    cur ^= 1;
  }
#pragma unroll
  for (int m = 0; m < 2; ++m) {
    int gm = bm + wm + m * 16 + ((lane >> 4) << 2);
#pragma unroll
    for (int n = 0; n < 4; ++n) {
      int gn = bn + wn + n * 16 + (lane & 15);
      if (gn < N) {
#pragma unroll
        for (int r = 0; r < 4; ++r) {
          float v = acc[m][n][r];
          if constexpr (__is_same(CT, ushort))
            C[(size_t)(gm + r) * N + gn] = f2bf(v);
          else
            C[(size_t)(gm + r) * N + gn] = v;
        }
      }
    }
  }
}

__global__ __launch_bounds__(256, 3) void gemm_f32k(
    const ushort* __restrict__ A, const ushort* __restrict__ B, float* __restrict__ C,
    int M, int N, int K) {
  __shared__ ushort As[2 * 64 * 64];
  __shared__ ushort Bs[2 * 128 * 64];
  gemm_body<float>(As, Bs, A, B, C, M, N, K, blockIdx.x, blockIdx.y);
}
__global__ __launch_bounds__(256, 3) void gemm_bf16k(
    const ushort* __restrict__ A, const ushort* __restrict__ B, ushort* __restrict__ C,
    int M, int N, int K) {
  __shared__ ushort As[2 * 64 * 64];
  __shared__ ushort Bs[2 * 128 * 64];
  gemm_body<ushort>(As, Bs, A, B, C, M, N, K, blockIdx.x, blockIdx.y);
}
// wqb (N=1024, y<8) and wkvb (N=1536, y>=8) in one launch: 64x20 = 1280 blocks
__global__ __launch_bounds__(256, 3) void gemm_dual(
    const ushort* __restrict__ Aq, const ushort* __restrict__ Bq, ushort* __restrict__ Cq,
    const ushort* __restrict__ Ak, const ushort* __restrict__ Bk, ushort* __restrict__ Ck) {
  __shared__ ushort As[2 * 64 * 64];
  __shared__ ushort Bs[2 * 128 * 64];
  if (blockIdx.y < 8)
    gemm_body<ushort>(As, Bs, Aq, Bq, Cq, SLEN, 1024, 512, blockIdx.x, blockIdx.y);
  else
    gemm_body<ushort>(As, Bs, Ak, Bk, Ck, SLEN, 1536, 512, blockIdx.x, blockIdx.y - 8);
}

// ---------------- LayerNorm over 512 cols (bf16 in, +optional k_pe rope) ----------------
__global__ __launch_bounds__(256) void ln_kernel(
    const ushort* __restrict__ in, int ldin, const float* __restrict__ w,
    const float* __restrict__ b, ushort* __restrict__ out,
    const float* __restrict__ cosT, const float* __restrict__ sinT,
    ushort* __restrict__ kpe) {
  int row = blockIdx.x, tid = threadIdx.x;
  const ushort* px = in + (size_t)row * ldin;
  float x0 = bf2f(px[tid]), x1 = bf2f(px[tid + 256]);
  float s = x0 + x1, sq = x0 * x0 + x1 * x1;
#pragma unroll
  for (int off = 32; off; off >>= 1) {
    s += __shfl_down(s, off);
    sq += __shfl_down(sq, off);
  }
  __shared__ float redS[4], redQ[4];
  int wave = tid >> 6, lane = tid & 63;
  if (lane == 0) { redS[wave] = s; redQ[wave] = sq; }
  __syncthreads();
  float st = redS[0] + redS[1] + redS[2] + redS[3];
  float sqt = redQ[0] + redQ[1] + redQ[2] + redQ[3];
  float mean = st * (1.0f / 512.0f);
  float var = sqt * (1.0f / 512.0f) - mean * mean;
  float rstd = rsqrtf(var + 1e-5f);
  out[(size_t)row * 512 + tid] = f2bf((x0 - mean) * rstd * w[tid] + b[tid]);
  out[(size_t)row * 512 + tid + 256] = f2bf((x1 - mean) * rstd * w[tid + 256] + b[tid + 256]);
  if (kpe != nullptr && tid < 32) {
    int p = tid >> 1;
    float xa = bf2f(px[512 + 2 * p]), xb = bf2f(px[512 + 2 * p + 1]);
    float c = cosT[(row << 4) + p], sn = sinT[(row << 4) + p];
    float v = (tid & 1) ? (xa * sn + xb * c) : (xa * c - xb * sn);
    kpe[(row << 5) + tid] = f2bf(v);
  }
}

// ---------------- q_full: copy nope + rope(q_pe), PRE-SCALED by 1/8*log2(e) ----------------
__global__ void build_qfull(const ushort* __restrict__ q, const float* __restrict__ cosT,
                            const float* __restrict__ sinT, ushort* __restrict__ qf) {
  const float SC = 0.125f * 1.44269504089f;
  int idx = blockIdx.x * blockDim.x + threadIdx.x;
  if (idx >= SLEN * EDIM) return;
  int d = idx & 63;
  int s = idx >> 10;
  const ushort* base = q + (size_t)(idx - d);
  float v;
  if (d < 32) {
    v = bf2f(base[d]);
  } else {
    int j = d - 32, p = j >> 1;
    float xa = bf2f(base[32 + 2 * p]), xb = bf2f(base[33 + 2 * p]);
    float c = cosT[(s << 4) + p], sn = sinT[(s << 4) + p];
    v = (j & 1) ? (xa * sn + xb * c) : (xa * c - xb * sn);
  }
  qf[idx] = f2bf(v * SC);
}

// ---------------- pack k_full + V^T with k-permutation: vt[h][hd][perm(s)] ----------------
__global__ __launch_bounds__(256) void pack_kv2(
    const ushort* __restrict__ kvdec, const ushort* __restrict__ kpe,
    ushort* __restrict__ kf, ushort* __restrict__ vt) {
  __shared__ ushort T[64 * 65];
  const int tid = threadIdx.x;
  const int sb = blockIdx.x, h = blockIdx.y;
  const int s0 = sb * 64;
#pragma unroll 4
  for (int i = 0; i < 16; ++i) {
    int s_loc = i * 4 + (tid >> 6);
    int d = tid & 63;
    const ushort* base = kvdec + ((size_t)(s0 + s_loc) * 16 + h) * 96;
    T[d * 65 + s_loc] = base[32 + d];
    ushort kval = (d < 32) ? base[d] : kpe[((s0 + s_loc) << 5) + (d - 32)];
    kf[(size_t)(s0 + s_loc) * EDIM + h * 64 + d] = kval;
  }
  __syncthreads();
#pragma unroll 4
  for (int i = 0; i < 16; ++i) {
    int hd = i * 4 + (tid >> 6);
    int s_off = tid & 63;
    // pi(s): s = nf*16 + g*4 + r -> (nf&1)*32 + g*8 + (nf>>1)*4 + r (involution)
    int sp = ((s_off >> 4) & 1) * 32 + ((s_off >> 2) & 3) * 8 + ((s_off >> 5) & 1) * 4 + (s_off & 3);
    vt[(size_t)(h * 64 + hd) * SLEN + s0 + sp] = T[hd * 65 + s_off];
  }
}

// ---------------- flash attention, KV-split partials, swapped-QK ----------------
__global__ __launch_bounds__(256, 5) void flash_part(
    const ushort* __restrict__ Qf, const ushort* __restrict__ Kf,
    const ushort* __restrict__ Vt, ushort* __restrict__ Opart, float* __restrict__ MLpart) {
  __shared__ ushort Klds[64 * 64];
  __shared__ ushort Vlds[64 * 64];
  const int tid = threadIdx.x, lane = tid & 63, wave = tid >> 6;
  const int p = NPAIR - 1 - blockIdx.x;
  const int h = blockIdx.y;
  int qb, ck;
  if (p < 16)      { qb = p;               ck = 0; }
  else if (p < 48) { int j = p - 16; qb = 16 + (j >> 1); ck = j & 1; }
  else if (p < 96) { int j = p - 48; qb = 32 + j / 3;    ck = j - 3 * (j / 3); }
  else             { int j = p - 96; qb = 48 + (j >> 2); ck = j & 3; }
  const int q0 = qb * 64;
  const int t0 = ck * 16;
  const int t1 = min(t0 + 16, qb + 1);

  short8 aq[2];
  {
    const ushort* qrow =
        Qf + (((size_t)(q0 + wave * 16 + (lane & 15)) * 16 + h) << 6) + ((lane >> 4) << 3);
    aq[0] = *(const short8*)qrow;
    aq[1] = *(const short8*)(qrow + 32);
  }
  f32x4 oacc[4];
#pragma unroll
  for (int nf = 0; nf < 4; ++nf) oacc[nf] = (f32x4)0.0f;
  float lacc = 0.0f, mrun = -1e30f;

  const int strow = wave * 16 + (lane >> 3);
  const int srcb = ((lane & 7) << 4) ^ (((lane >> 3) & 7) << 4);

  for (int kb = t0; kb < t1; ++kb) {
#pragma unroll
    for (int c = 0; c < 2; ++c) {
      int r = strow + c * 8;
      const ushort* gk = Kf + (((size_t)(kb * 64 + r) * 16 + h) << 6) + (srcb >> 1);
      GLD_LDS16(gk, &Klds[(wave * 16 + c * 8) * 64]);
      const ushort* gv = Vt + (size_t)(h * 64 + r) * SLEN + kb * 64 + (srcb >> 1);
      GLD_LDS16(gv, &Vlds[(wave * 16 + c * 8) * 64]);
    }
    __syncthreads();

    // ---- S^T = K * Q^T : sfr[nf][r] = S[q=lane&15][k = nf*16 + (lane>>4)*4 + r] ----
    f32x4 sfr[4];
#pragma unroll
    for (int nf = 0; nf < 4; ++nf) sfr[nf] = (f32x4)0.0f;
#pragma unroll
    for (int kk = 0; kk < 2; ++kk) {
#pragma unroll
      for (int nf = 0; nf < 4; ++nf) {
        int row = nf * 16 + (lane & 15);
        int cb = (kk * 64 + ((lane >> 4) << 4)) ^ ((row & 7) << 4);
        short8 ak = *(const short8*)((const char*)Klds + row * 128 + cb);
        sfr[nf] = __builtin_amdgcn_mfma_f32_16x16x32_bf16(ak, aq[kk], sfr[nf], 0, 0, 0);
      }
    }
    if (kb == qb) {
      const int qloc = wave * 16 + (lane & 15);
      const int kg = (lane >> 4) << 2;
#pragma unroll
      for (int nf = 0; nf < 4; ++nf) {
#pragma unroll
        for (int r = 0; r < 4; ++r)
          if (nf * 16 + kg + r > qloc) sfr[nf][r] = -1e30f;
      }
    }
    float pm = -1e30f;
#pragma unroll
    for (int nf = 0; nf < 4; ++nf)
#pragma unroll
      for (int r = 0; r < 4; ++r) pm = fmaxf(pm, sfr[nf][r]);
    pm = fmaxf(pm, __shfl_xor(pm, 16));
    pm = fmaxf(pm, __shfl_xor(pm, 32));
    if (__any(pm > mrun + 8.0f)) {
      float mnew = fmaxf(mrun, pm);
      float corr = exp2f(mrun - mnew);
      mrun = mnew;
      lacc *= corr;
      const int gbase = lane & 48;
#pragma unroll
      for (int r = 0; r < 4; ++r) {
        float cB = __shfl(corr, gbase + ((lane >> 4) << 2) + r);
#pragma unroll
        for (int nf = 0; nf < 4; ++nf) oacc[nf][r] *= cB;
      }
    }
    float ps = 0.0f;
#pragma unroll
    for (int nf = 0; nf < 4; ++nf)
#pragma unroll
      for (int r = 0; r < 4; ++r) {
        float pv = exp2f(sfr[nf][r] - mrun);
        sfr[nf][r] = pv;
        ps += pv;
      }
    ps += __shfl_xor(ps, 16);
    ps += __shfl_xor(ps, 32);
    lacc += ps;
    short8 ap[2];
#pragma unroll
    for (int kk = 0; kk < 2; ++kk) {
      union { uint32_t u[4]; short8 s; } pk;
      pk.u[0] = cvt_pk_bf16(sfr[kk][0], sfr[kk][1]);
      pk.u[1] = cvt_pk_bf16(sfr[kk][2], sfr[kk][3]);
      pk.u[2] = cvt_pk_bf16(sfr[kk + 2][0], sfr[kk + 2][1]);
      pk.u[3] = cvt_pk_bf16(sfr[kk + 2][2], sfr[kk + 2][3]);
      ap[kk] = pk.s;
    }
#pragma unroll
    for (int nf = 0; nf < 4; ++nf) {
#pragma unroll
      for (int kk = 0; kk < 2; ++kk) {
        int row = nf * 16 + (lane & 15);
        int cb = (kk * 64 + ((lane >> 4) << 4)) ^ ((row & 7) << 4);
        short8 bv = *(const short8*)((const char*)Vlds + row * 128 + cb);
        oacc[nf] = __builtin_amdgcn_mfma_f32_16x16x32_bf16(ap[kk], bv, oacc[nf], 0, 0, 0);
      }
    }
    __syncthreads();
  }
  // ---- write bf16 partials ----
  const size_t pb = (size_t)h * NPAIR + p;
#pragma unroll
  for (int nf = 0; nf < 4; ++nf) {
#pragma unroll
    for (int r = 0; r < 4; ++r) {
      int row = wave * 16 + ((lane >> 4) << 2) + r;
      int d = nf * 16 + (lane & 15);
      Opart[(pb * 64 + row) * 64 + d] = f2bf(oacc[nf][r]);
    }
  }
  if (lane < 16) {
    MLpart[pb * 128 + wave * 16 + lane] = mrun;
    MLpart[pb * 128 + 64 + wave * 16 + lane] = lacc;
  }
}

// ---------------- combine partials -> attn bf16 [s][h*64+d] ----------------
__global__ __launch_bounds__(256) void flash_combine(
    const ushort* __restrict__ Opart, const float* __restrict__ MLpart,
    ushort* __restrict__ attn) {
  const int qb = blockIdx.x, h = blockIdx.y;
  const int g = qb >> 4, n = g + 1;
  const int base = (g == 0 ? 0 : g == 1 ? 16 : g == 2 ? 48 : 96) + (qb - (g << 4)) * n;
  __shared__ float mS[4][64], lS[4][64];
  const int tid = threadIdx.x;
  for (int i = tid; i < n * 64; i += 256) {
    int part = i >> 6, row = i & 63;
    size_t pb = (size_t)h * NPAIR + base + part;
    mS[part][row] = MLpart[pb * 128 + row];
    lS[part][row] = MLpart[pb * 128 + 64 + row];
  }
  __syncthreads();
  const int d = tid & 63, rg = tid >> 6;
#pragma unroll 4
  for (int k = 0; k < 16; ++k) {
    int row = rg * 16 + k;
    float M = mS[0][row];
    for (int i = 1; i < n; ++i) M = fmaxf(M, mS[i][row]);
    float L = 0.0f, acc = 0.0f;
    for (int i = 0; i < n; ++i) {
      float w = exp2f(mS[i][row] - M);
      L += lS[i][row] * w;
      acc += bf2f(Opart[(((size_t)h * NPAIR + base + i) * 64 + row) * 64 + d]) * w;
    }
    attn[(size_t)(qb * 64 + row) * EDIM + h * 64 + d] = f2bf(acc / L);
  }
}

// ---------------- launcher ----------------
extern "C" void kernel_launch(void* const* d_in, const int* in_sizes, int n_in,
                              void* d_out, int out_size, void* d_ws, size_t ws_size,
                              hipStream_t stream) {
  const float* x     = (const float*)d_in[0];
  const float* Wqa   = (const float*)d_in[2];
  const float* qa_w  = (const float*)d_in[3];
  const float* qa_b  = (const float*)d_in[4];
  const float* Wqb   = (const float*)d_in[5];
  const float* Wkva  = (const float*)d_in[6];
  const float* kva_w = (const float*)d_in[7];
  const float* kva_b = (const float*)d_in[8];
  const float* Wkvb  = (const float*)d_in[9];
  const float* Wo    = (const float*)d_in[10];
  float* out = (float*)d_out;

  char* ws = (char*)d_ws;
  size_t off = 0;
  auto alloc = [&](size_t bytes) {
    char* p = ws + off;
    off += (bytes + 255) & ~(size_t)255;
    return p;
  };
  ushort* xb      = (ushort*)alloc((size_t)SLEN * EDIM * 2);
  ushort* wqkva_b = (ushort*)alloc((size_t)1056 * 1024 * 2);
  ushort* wqb_b   = (ushort*)alloc((size_t)1024 * 512 * 2);
  ushort* wkvb_b  = (ushort*)alloc((size_t)1536 * 512 * 2);
  ushort* wo_b    = (ushort*)alloc((size_t)1024 * 1024 * 2);
  float*  cosT    = (float*)alloc((size_t)SLEN * 16 * 4);
  float*  sinT    = (float*)alloc((size_t)SLEN * 16 * 4);
  ushort* qc_b    = (ushort*)alloc((size_t)SLEN * 512 * 2);
  ushort* qf_b    = (ushort*)alloc((size_t)SLEN * EDIM * 2);
  ushort* ckv_b   = (ushort*)alloc((size_t)SLEN * 512 * 2);
  ushort* kpe_b   = (ushort*)alloc((size_t)SLEN * 32 * 2);
  ushort* kf_b    = (ushort*)alloc((size_t)SLEN * EDIM * 2);
  ushort* vt_b    = (ushort*)alloc((size_t)SLEN * EDIM * 2);
  ushort* attn_b  = (ushort*)alloc((size_t)SLEN * EDIM * 2);
  ushort* qakv_bf = (ushort*)alloc((size_t)SLEN * 1056 * 2);
  float*  MLpart  = (float*)alloc((size_t)NH * NPAIR * 128 * 4);
  // q_bf (8.39MB) + kvdec_bf (12.58MB) alias Opart (20.97MB): both dead pre-flash
  char* RB = alloc((size_t)SLEN * 1024 * 2 + (size_t)SLEN * 1536 * 2);
  ushort* q_bf     = (ushort*)RB;
  ushort* kvdec_bf = (ushort*)(RB + (size_t)SLEN * 1024 * 2);
  ushort* Opart    = (ushort*)RB;

  // ---- fused casts ----
  CastArgs ca;
  ca.seg[0] = { (const float4*)x,    xb,                               SLEN * EDIM / 4 };
  ca.seg[1] = { (const float4*)Wqa,  wqkva_b,                          512 * 1024 / 4 };
  ca.seg[2] = { (const float4*)Wkva, wqkva_b + (size_t)512 * 1024,     544 * 1024 / 4 };
  ca.seg[3] = { (const float4*)Wqb,  wqb_b,                            1024 * 512 / 4 };
  ca.seg[4] = { (const float4*)Wkvb, wkvb_b,                           1536 * 512 / 4 };
  ca.seg[5] = { (const float4*)Wo,   wo_b,                             1024 * 1024 / 4 };
  ca.total4 = ca.seg[0].n4 + ca.seg[1].n4 + ca.seg[2].n4 + ca.seg[3].n4 + ca.seg[4].n4 + ca.seg[5].n4;
  cast_all<<<dim3(2048), 256, 0, stream>>>(ca);
  rope_table<<<dim3((SLEN * 16 + 255) / 256), 256, 0, stream>>>(cosT, sinT);

  // merged qa+kva projection (bf16 out)
  gemm_bf16k<<<dim3(64, 9), 256, 0, stream>>>(xb, wqkva_b, qakv_bf, SLEN, 1056, 1024);
  ln_kernel<<<dim3(SLEN), 256, 0, stream>>>(qakv_bf, 1056, qa_w, qa_b, qc_b, nullptr, nullptr, nullptr);
  ln_kernel<<<dim3(SLEN), 256, 0, stream>>>(qakv_bf + 512, 1056, kva_w, kva_b, ckv_b, cosT, sinT, kpe_b);
  // wqb + wkvb in one launch (bf16 out)
  gemm_dual<<<dim3(64, 20), 256, 0, stream>>>(qc_b, wqb_b, q_bf, ckv_b, wkvb_b, kvdec_bf);
  build_qfull<<<dim3(SLEN * EDIM / 256), 256, 0, stream>>>(q_bf, cosT, sinT, qf_b);
  pack_kv2<<<dim3(64, 16), 256, 0, stream>>>(kvdec_bf, kpe_b, kf_b, vt_b);

  flash_part<<<dim3(NPAIR, 16), 256, 0, stream>>>(qf_b, kf_b, vt_b, Opart, MLpart);
  flash_combine<<<dim3(64, 16), 256, 0, stream>>>(Opart, MLpart, attn_b);
  gemm_f32k<<<dim3(64, 8), 256, 0, stream>>>(attn_b, wo_b, out, SLEN, 1024, 1024);

  (void)in_sizes; (void)n_in; (void)out_size; (void)ws_size;
}

// Round 8
// 189.384 us; speedup vs baseline: 2.3769x; 1.0301x over previous
//
#include <hip/hip_runtime.h>
#include <hip/hip_bf16.h>
#include <stdint.h>

// ---------------- MLA decoder self-attention, bf16-MFMA pipeline ----------------
// S=4096 E=1024 H=16 HD=64 ROPE=32 NOPE=32 QR=512 KVR=512, causal.
// R7: flash K/V double-buffered (1 barrier/tile); q-rope fused into dual-GEMM
// epilogue (shfl_xor partner); LN pair merged into one launch.

#define SLEN 4096
#define EDIM 1024
#define NH   16
#define NPAIR 160   // sum over qb of floor(qb/16)+1

typedef __attribute__((ext_vector_type(8))) short short8;
typedef __attribute__((ext_vector_type(4))) float f32x4;

__device__ __forceinline__ ushort f2bf(float f) {
  __hip_bfloat16 h = __float2bfloat16(f);
  ushort u; __builtin_memcpy(&u, &h, 2); return u;
}
__device__ __forceinline__ float bf2f(ushort u) {
  uint32_t x = (uint32_t)u << 16;
  float f; __builtin_memcpy(&f, &x, 4); return f;
}
__device__ __forceinline__ uint32_t cvt_pk_bf16(float lo, float hi) {
  uint32_t r;
  asm("v_cvt_pk_bf16_f32 %0, %1, %2" : "=v"(r) : "v"(lo), "v"(hi));
  return r;
}

#define GLD_LDS16(g, l) __builtin_amdgcn_global_load_lds(                      \
    (const __attribute__((address_space(1))) uint32_t*)(g),                    \
    (__attribute__((address_space(3))) uint32_t*)(l), 16, 0, 0)

// ---------------- fused cast: 6 tensors f32 -> bf16, one launch ----------------
struct CastSeg { const float4* src; ushort* dst; int n4; };
struct CastArgs { CastSeg seg[6]; int total4; };
__global__ void cast_all(CastArgs a) {
  int i = blockIdx.x * blockDim.x + threadIdx.x;
  int stride = gridDim.x * blockDim.x;
  for (; i < a.total4; i += stride) {
    int idx = i, s = 0;
    while (idx >= a.seg[s].n4) { idx -= a.seg[s].n4; ++s; }
    float4 v = a.seg[s].src[idx];
    ushort4 o;
    o.x = f2bf(v.x); o.y = f2bf(v.y); o.z = f2bf(v.z); o.w = f2bf(v.w);
    *(ushort4*)(a.seg[s].dst + (size_t)idx * 4) = o;
  }
}

// ---------------- rope tables: cos/sin[s][16] ----------------
__global__ void rope_table(float* __restrict__ cosT, float* __restrict__ sinT) {
  int idx = blockIdx.x * blockDim.x + threadIdx.x;
  if (idx >= SLEN * 16) return;
  int s = idx >> 4, i = idx & 15;
  float inv = expf(-((float)(2 * i) / 32.0f) * logf(10000.0f));
  float ang = (float)s * inv;
  cosT[idx] = cosf(ang);
  sinT[idx] = sinf(ang);
}

// ---------------- GEMM body: C = A*B^T, 64x128 tile, 2-phase double-buffered ----------------
// ROPE epilogue: per-head rope on cols d>=32 via shfl_xor(v,1) partner + *SC (q_full fusion).
template <typename CT, bool ROPE>
__device__ __forceinline__ void gemm_body(
    ushort* As, ushort* Bs,
    const ushort* __restrict__ A, const ushort* __restrict__ B, CT* __restrict__ C,
    int M, int N, int K, int bx, int by,
    const float* __restrict__ cosT, const float* __restrict__ sinT) {
  const int tid = threadIdx.x;
  const int lane = tid & 63, wave = tid >> 6;
  const int bm = bx * 64, bn = by * 128;
  const int wm = (wave >> 1) * 32, wn = (wave & 1) * 64;

  f32x4 acc[2][4];
#pragma unroll
  for (int m = 0; m < 2; ++m)
#pragma unroll
    for (int n = 0; n < 4; ++n) acc[m][n] = (f32x4)0.0f;

  const int srow = lane >> 3;
  const int scb = (lane & 7) << 4;
  const int srcb = scb ^ ((srow & 7) << 4);

  auto stage = [&](int k0, int buf) {
#pragma unroll
    for (int c = 0; c < 2; ++c) {
      int r = wave * 16 + c * 8 + srow;
      const ushort* ga = A + (size_t)(bm + r) * K + k0 + (srcb >> 1);
      GLD_LDS16(ga, As + buf * 4096 + (wave * 16 + c * 8) * 64);
    }
#pragma unroll
    for (int c = 0; c < 4; ++c) {
      int r = wave * 32 + c * 8 + srow;
      int rb = bn + r; if (rb >= N) rb = N - 1;
      const ushort* gb = B + (size_t)rb * K + k0 + (srcb >> 1);
      GLD_LDS16(gb, Bs + buf * 8192 + (wave * 32 + c * 8) * 64);
    }
  };

  stage(0, 0);
  __syncthreads();
  int cur = 0;
  for (int k0 = 0; k0 < K; k0 += 64) {
    if (k0 + 64 < K) stage(k0 + 64, cur ^ 1);
    const char* Ab = (const char*)(As + cur * 4096);
    const char* Bb = (const char*)(Bs + cur * 8192);
#pragma unroll
    for (int kk = 0; kk < 2; ++kk) {
      short8 af[2], bf[4];
#pragma unroll
      for (int m = 0; m < 2; ++m) {
        int row = wm + m * 16 + (lane & 15);
        int cb = (kk * 64 + ((lane >> 4) << 4)) ^ ((row & 7) << 4);
        af[m] = *(const short8*)(Ab + row * 128 + cb);
      }
#pragma unroll
      for (int n = 0; n < 4; ++n) {
        int row = wn + n * 16 + (lane & 15);
        int cb = (kk * 64 + ((lane >> 4) << 4)) ^ ((row & 7) << 4);
        bf[n] = *(const short8*)(Bb + row * 128 + cb);
      }
#pragma unroll
      for (int m = 0; m < 2; ++m)
#pragma unroll
        for (int n = 0; n < 4; ++n)
          acc[m][n] = __builtin_amdgcn_mfma_f32_16x16x32_bf16(af[m], bf[n], acc[m][n], 0, 0, 0);
    }
    __syncthreads();
    cur ^= 1;
  }
  const float SCQ = 0.125f * 1.44269504089f;  // 1/sqrt(64) * log2(e)
#pragma unroll
  for (int m = 0; m < 2; ++m) {
    int gm = bm + wm + m * 16 + ((lane >> 4) << 2);
#pragma unroll
    for (int n = 0; n < 4; ++n) {
      int gn = bn + wn + n * 16 + (lane & 15);
      if (gn < N) {
#pragma unroll
        for (int r = 0; r < 4; ++r) {
          float v = acc[m][n][r];
          if constexpr (ROPE) {
            float partner = __shfl_xor(v, 1);  // col gn^1, same rows
            int d = gn & 63;
            if (d >= 32) {
              int s = gm + r, pidx = (d - 32) >> 1;
              float c = cosT[(s << 4) + pidx], sn = sinT[(s << 4) + pidx];
              v = (gn & 1) ? (partner * sn + v * c) : (v * c - partner * sn);
            }
            v *= SCQ;
          }
          if constexpr (__is_same(CT, ushort))
            C[(size_t)(gm + r) * N + gn] = f2bf(v);
          else
            C[(size_t)(gm + r) * N + gn] = v;
        }
      }
    }
  }
}

__global__ __launch_bounds__(256, 3) void gemm_f32k(
    const ushort* __restrict__ A, const ushort* __restrict__ B, float* __restrict__ C,
    int M, int N, int K) {
  __shared__ ushort As[2 * 64 * 64];
  __shared__ ushort Bs[2 * 128 * 64];
  gemm_body<float, false>(As, Bs, A, B, C, M, N, K, blockIdx.x, blockIdx.y, nullptr, nullptr);
}
__global__ __launch_bounds__(256, 3) void gemm_bf16k(
    const ushort* __restrict__ A, const ushort* __restrict__ B, ushort* __restrict__ C,
    int M, int N, int K) {
  __shared__ ushort As[2 * 64 * 64];
  __shared__ ushort Bs[2 * 128 * 64];
  gemm_body<ushort, false>(As, Bs, A, B, C, M, N, K, blockIdx.x, blockIdx.y, nullptr, nullptr);
}
// wqb (N=1024, y<8, rope+scale epilogue -> q_full) and wkvb (N=1536, y>=8)
__global__ __launch_bounds__(256, 3) void gemm_dual(
    const ushort* __restrict__ Aq, const ushort* __restrict__ Bq, ushort* __restrict__ Cq,
    const ushort* __restrict__ Ak, const ushort* __restrict__ Bk, ushort* __restrict__ Ck,
    const float* __restrict__ cosT, const float* __restrict__ sinT) {
  __shared__ ushort As[2 * 64 * 64];
  __shared__ ushort Bs[2 * 128 * 64];
  if (blockIdx.y < 8)
    gemm_body<ushort, true>(As, Bs, Aq, Bq, Cq, SLEN, 1024, 512, blockIdx.x, blockIdx.y, cosT, sinT);
  else
    gemm_body<ushort, false>(As, Bs, Ak, Bk, Ck, SLEN, 1536, 512, blockIdx.x, blockIdx.y - 8, nullptr, nullptr);
}

// ---------------- LayerNorm both halves (bf16 in): blocks 0..4095 q, 4096..8191 kv ----------------
__global__ __launch_bounds__(256) void ln_both(
    const ushort* __restrict__ qakv,
    const float* __restrict__ qa_w, const float* __restrict__ qa_b,
    const float* __restrict__ kva_w, const float* __restrict__ kva_b,
    ushort* __restrict__ qc, ushort* __restrict__ ckv,
    const float* __restrict__ cosT, const float* __restrict__ sinT,
    ushort* __restrict__ kpe) {
  const int row = blockIdx.x & 4095;
  const bool iskv = blockIdx.x >= 4096;
  const int tid = threadIdx.x;
  const ushort* px = qakv + (size_t)row * 1056 + (iskv ? 512 : 0);
  const float* w = iskv ? kva_w : qa_w;
  const float* b = iskv ? kva_b : qa_b;
  ushort* out = (iskv ? ckv : qc) + (size_t)row * 512;
  float x0 = bf2f(px[tid]), x1 = bf2f(px[tid + 256]);
  float s = x0 + x1, sq = x0 * x0 + x1 * x1;
#pragma unroll
  for (int off = 32; off; off >>= 1) {
    s += __shfl_down(s, off);
    sq += __shfl_down(sq, off);
  }
  __shared__ float redS[4], redQ[4];
  int wave = tid >> 6, lane = tid & 63;
  if (lane == 0) { redS[wave] = s; redQ[wave] = sq; }
  __syncthreads();
  float st = redS[0] + redS[1] + redS[2] + redS[3];
  float sqt = redQ[0] + redQ[1] + redQ[2] + redQ[3];
  float mean = st * (1.0f / 512.0f);
  float var = sqt * (1.0f / 512.0f) - mean * mean;
  float rstd = rsqrtf(var + 1e-5f);
  out[tid] = f2bf((x0 - mean) * rstd * w[tid] + b[tid]);
  out[tid + 256] = f2bf((x1 - mean) * rstd * w[tid + 256] + b[tid + 256]);
  if (iskv && tid < 32) {
    int p = tid >> 1;
    float xa = bf2f(px[512 + 2 * p]), xb = bf2f(px[512 + 2 * p + 1]);
    float c = cosT[(row << 4) + p], sn = sinT[(row << 4) + p];
    float v = (tid & 1) ? (xa * sn + xb * c) : (xa * c - xb * sn);
    kpe[(row << 5) + tid] = f2bf(v);
  }
}

// ---------------- pack k_full + V^T with k-permutation: vt[h][hd][perm(s)] ----------------
__global__ __launch_bounds__(256) void pack_kv2(
    const ushort* __restrict__ kvdec, const ushort* __restrict__ kpe,
    ushort* __restrict__ kf, ushort* __restrict__ vt) {
  __shared__ ushort T[64 * 65];
  const int tid = threadIdx.x;
  const int sb = blockIdx.x, h = blockIdx.y;
  const int s0 = sb * 64;
#pragma unroll 4
  for (int i = 0; i < 16; ++i) {
    int s_loc = i * 4 + (tid >> 6);
    int d = tid & 63;
    const ushort* base = kvdec + ((size_t)(s0 + s_loc) * 16 + h) * 96;
    T[d * 65 + s_loc] = base[32 + d];
    ushort kval = (d < 32) ? base[d] : kpe[((s0 + s_loc) << 5) + (d - 32)];
    kf[(size_t)(s0 + s_loc) * EDIM + h * 64 + d] = kval;
  }
  __syncthreads();
#pragma unroll 4
  for (int i = 0; i < 16; ++i) {
    int hd = i * 4 + (tid >> 6);
    int s_off = tid & 63;
    // pi(s): s = nf*16 + g*4 + r -> (nf&1)*32 + g*8 + (nf>>1)*4 + r (involution)
    int sp = ((s_off >> 4) & 1) * 32 + ((s_off >> 2) & 3) * 8 + ((s_off >> 5) & 1) * 4 + (s_off & 3);
    vt[(size_t)(h * 64 + hd) * SLEN + s0 + sp] = T[hd * 65 + s_off];
  }
}

// ---------------- flash attention, KV-split partials, swapped-QK, K/V dbuf ----------------
__global__ __launch_bounds__(256, 4) void flash_part(
    const ushort* __restrict__ Qf, const ushort* __restrict__ Kf,
    const ushort* __restrict__ Vt, ushort* __restrict__ Opart, float* __restrict__ MLpart) {
  __shared__ ushort Klds[2][64 * 64];
  __shared__ ushort Vlds[2][64 * 64];
  const int tid = threadIdx.x, lane = tid & 63, wave = tid >> 6;
  const int p = NPAIR - 1 - blockIdx.x;
  const int h = blockIdx.y;
  int qb, ck;
  if (p < 16)      { qb = p;               ck = 0; }
  else if (p < 48) { int j = p - 16; qb = 16 + (j >> 1); ck = j & 1; }
  else if (p < 96) { int j = p - 48; qb = 32 + j / 3;    ck = j - 3 * (j / 3); }
  else             { int j = p - 96; qb = 48 + (j >> 2); ck = j & 3; }
  const int q0 = qb * 64;
  const int t0 = ck * 16;
  const int t1 = min(t0 + 16, qb + 1);

  short8 aq[2];
  {
    const ushort* qrow =
        Qf + (((size_t)(q0 + wave * 16 + (lane & 15)) * 16 + h) << 6) + ((lane >> 4) << 3);
    aq[0] = *(const short8*)qrow;
    aq[1] = *(const short8*)(qrow + 32);
  }
  f32x4 oacc[4];
#pragma unroll
  for (int nf = 0; nf < 4; ++nf) oacc[nf] = (f32x4)0.0f;
  float lacc = 0.0f, mrun = -1e30f;

  const int strow = wave * 16 + (lane >> 3);
  const int srcb = ((lane & 7) << 4) ^ (((lane >> 3) & 7) << 4);

  auto stage = [&](int kb, int buf) {
#pragma unroll
    for (int c = 0; c < 2; ++c) {
      int r = strow + c * 8;
      const ushort* gk = Kf + (((size_t)(kb * 64 + r) * 16 + h) << 6) + (srcb >> 1);
      GLD_LDS16(gk, &Klds[buf][(wave * 16 + c * 8) * 64]);
      const ushort* gv = Vt + (size_t)(h * 64 + r) * SLEN + kb * 64 + (srcb >> 1);
      GLD_LDS16(gv, &Vlds[buf][(wave * 16 + c * 8) * 64]);
    }
  };

  stage(t0, 0);
  __syncthreads();
  int cur = 0;
  for (int kb = t0; kb < t1; ++kb) {
    if (kb + 1 < t1) stage(kb + 1, cur ^ 1);  // prefetch under compute

    // ---- S^T = K * Q^T : sfr[nf][r] = S[q=lane&15][k = nf*16 + (lane>>4)*4 + r] ----
    f32x4 sfr[4];
#pragma unroll
    for (int nf = 0; nf < 4; ++nf) sfr[nf] = (f32x4)0.0f;
#pragma unroll
    for (int kk = 0; kk < 2; ++kk) {
#pragma unroll
      for (int nf = 0; nf < 4; ++nf) {
        int row = nf * 16 + (lane & 15);
        int cb = (kk * 64 + ((lane >> 4) << 4)) ^ ((row & 7) << 4);
        short8 ak = *(const short8*)((const char*)&Klds[cur][0] + row * 128 + cb);
        sfr[nf] = __builtin_amdgcn_mfma_f32_16x16x32_bf16(ak, aq[kk], sfr[nf], 0, 0, 0);
      }
    }
    if (kb == qb) {
      const int qloc = wave * 16 + (lane & 15);
      const int kg = (lane >> 4) << 2;
#pragma unroll
      for (int nf = 0; nf < 4; ++nf) {
#pragma unroll
        for (int r = 0; r < 4; ++r)
          if (nf * 16 + kg + r > qloc) sfr[nf][r] = -1e30f;
      }
    }
    float pm = -1e30f;
#pragma unroll
    for (int nf = 0; nf < 4; ++nf)
#pragma unroll
      for (int r = 0; r < 4; ++r) pm = fmaxf(pm, sfr[nf][r]);
    pm = fmaxf(pm, __shfl_xor(pm, 16));
    pm = fmaxf(pm, __shfl_xor(pm, 32));
    if (__any(pm > mrun + 8.0f)) {
      float mnew = fmaxf(mrun, pm);
      float corr = exp2f(mrun - mnew);
      mrun = mnew;
      lacc *= corr;
      const int gbase = lane & 48;
#pragma unroll
      for (int r = 0; r < 4; ++r) {
        float cB = __shfl(corr, gbase + ((lane >> 4) << 2) + r);
#pragma unroll
        for (int nf = 0; nf < 4; ++nf) oacc[nf][r] *= cB;
      }
    }
    float ps = 0.0f;
#pragma unroll
    for (int nf = 0; nf < 4; ++nf)
#pragma unroll
      for (int r = 0; r < 4; ++r) {
        float pv = exp2f(sfr[nf][r] - mrun);
        sfr[nf][r] = pv;
        ps += pv;
      }
    ps += __shfl_xor(ps, 16);
    ps += __shfl_xor(ps, 32);
    lacc += ps;
    short8 ap[2];
#pragma unroll
    for (int kk = 0; kk < 2; ++kk) {
      union { uint32_t u[4]; short8 s; } pk;
      pk.u[0] = cvt_pk_bf16(sfr[kk][0], sfr[kk][1]);
      pk.u[1] = cvt_pk_bf16(sfr[kk][2], sfr[kk][3]);
      pk.u[2] = cvt_pk_bf16(sfr[kk + 2][0], sfr[kk + 2][1]);
      pk.u[3] = cvt_pk_bf16(sfr[kk + 2][2], sfr[kk + 2][3]);
      ap[kk] = pk.s;
    }
#pragma unroll
    for (int nf = 0; nf < 4; ++nf) {
#pragma unroll
      for (int kk = 0; kk < 2; ++kk) {
        int row = nf * 16 + (lane & 15);
        int cb = (kk * 64 + ((lane >> 4) << 4)) ^ ((row & 7) << 4);
        short8 bv = *(const short8*)((const char*)&Vlds[cur][0] + row * 128 + cb);
        oacc[nf] = __builtin_amdgcn_mfma_f32_16x16x32_bf16(ap[kk], bv, oacc[nf], 0, 0, 0);
      }
    }
    __syncthreads();  // all waves done with buf[cur]; stage(kb+1) drained
    cur ^= 1;
  }
  // ---- write bf16 partials ----
  const size_t pb = (size_t)h * NPAIR + p;
#pragma unroll
  for (int nf = 0; nf < 4; ++nf) {
#pragma unroll
    for (int r = 0; r < 4; ++r) {
      int row = wave * 16 + ((lane >> 4) << 2) + r;
      int d = nf * 16 + (lane & 15);
      Opart[(pb * 64 + row) * 64 + d] = f2bf(oacc[nf][r]);
    }
  }
  if (lane < 16) {
    MLpart[pb * 128 + wave * 16 + lane] = mrun;
    MLpart[pb * 128 + 64 + wave * 16 + lane] = lacc;
  }
}

// ---------------- combine partials -> attn bf16 [s][h*64+d] ----------------
__global__ __launch_bounds__(256) void flash_combine(
    const ushort* __restrict__ Opart, const float* __restrict__ MLpart,
    ushort* __restrict__ attn) {
  const int qb = blockIdx.x, h = blockIdx.y;
  const int g = qb >> 4, n = g + 1;
  const int base = (g == 0 ? 0 : g == 1 ? 16 : g == 2 ? 48 : 96) + (qb - (g << 4)) * n;
  __shared__ float mS[4][64], lS[4][64];
  const int tid = threadIdx.x;
  for (int i = tid; i < n * 64; i += 256) {
    int part = i >> 6, row = i & 63;
    size_t pb = (size_t)h * NPAIR + base + part;
    mS[part][row] = MLpart[pb * 128 + row];
    lS[part][row] = MLpart[pb * 128 + 64 + row];
  }
  __syncthreads();
  const int d = tid & 63, rg = tid >> 6;
#pragma unroll 4
  for (int k = 0; k < 16; ++k) {
    int row = rg * 16 + k;
    float M = mS[0][row];
    for (int i = 1; i < n; ++i) M = fmaxf(M, mS[i][row]);
    float L = 0.0f, acc = 0.0f;
    for (int i = 0; i < n; ++i) {
      float w = exp2f(mS[i][row] - M);
      L += lS[i][row] * w;
      acc += bf2f(Opart[(((size_t)h * NPAIR + base + i) * 64 + row) * 64 + d]) * w;
    }
    attn[(size_t)(qb * 64 + row) * EDIM + h * 64 + d] = f2bf(acc / L);
  }
}

// ---------------- launcher ----------------
extern "C" void kernel_launch(void* const* d_in, const int* in_sizes, int n_in,
                              void* d_out, int out_size, void* d_ws, size_t ws_size,
                              hipStream_t stream) {
  const float* x     = (const float*)d_in[0];
  const float* Wqa   = (const float*)d_in[2];
  const float* qa_w  = (const float*)d_in[3];
  const float* qa_b  = (const float*)d_in[4];
  const float* Wqb   = (const float*)d_in[5];
  const float* Wkva  = (const float*)d_in[6];
  const float* kva_w = (const float*)d_in[7];
  const float* kva_b = (const float*)d_in[8];
  const float* Wkvb  = (const float*)d_in[9];
  const float* Wo    = (const float*)d_in[10];
  float* out = (float*)d_out;

  char* ws = (char*)d_ws;
  size_t off = 0;
  auto alloc = [&](size_t bytes) {
    char* p = ws + off;
    off += (bytes + 255) & ~(size_t)255;
    return p;
  };
  ushort* xb      = (ushort*)alloc((size_t)SLEN * EDIM * 2);
  ushort* wqkva_b = (ushort*)alloc((size_t)1056 * 1024 * 2);
  ushort* wqb_b   = (ushort*)alloc((size_t)1024 * 512 * 2);
  ushort* wkvb_b  = (ushort*)alloc((size_t)1536 * 512 * 2);
  ushort* wo_b    = (ushort*)alloc((size_t)1024 * 1024 * 2);
  float*  cosT    = (float*)alloc((size_t)SLEN * 16 * 4);
  float*  sinT    = (float*)alloc((size_t)SLEN * 16 * 4);
  ushort* qc_b    = (ushort*)alloc((size_t)SLEN * 512 * 2);
  ushort* qf_b    = (ushort*)alloc((size_t)SLEN * EDIM * 2);
  ushort* ckv_b   = (ushort*)alloc((size_t)SLEN * 512 * 2);
  ushort* kpe_b   = (ushort*)alloc((size_t)SLEN * 32 * 2);
  ushort* kf_b    = (ushort*)alloc((size_t)SLEN * EDIM * 2);
  ushort* vt_b    = (ushort*)alloc((size_t)SLEN * EDIM * 2);
  ushort* attn_b  = (ushort*)alloc((size_t)SLEN * EDIM * 2);
  ushort* qakv_bf = (ushort*)alloc((size_t)SLEN * 1056 * 2);
  float*  MLpart  = (float*)alloc((size_t)NH * NPAIR * 128 * 4);
  // kvdec_bf (12.58MB, dead before flash) aliases Opart (20.97MB)
  char* RB = alloc((size_t)NH * NPAIR * 64 * 64 * 2);
  ushort* kvdec_bf = (ushort*)RB;
  ushort* Opart    = (ushort*)RB;

  // ---- fused casts ----
  CastArgs ca;
  ca.seg[0] = { (const float4*)x,    xb,                               SLEN * EDIM / 4 };
  ca.seg[1] = { (const float4*)Wqa,  wqkva_b,                          512 * 1024 / 4 };
  ca.seg[2] = { (const float4*)Wkva, wqkva_b + (size_t)512 * 1024,     544 * 1024 / 4 };
  ca.seg[3] = { (const float4*)Wqb,  wqb_b,                            1024 * 512 / 4 };
  ca.seg[4] = { (const float4*)Wkvb, wkvb_b,                           1536 * 512 / 4 };
  ca.seg[5] = { (const float4*)Wo,   wo_b,                             1024 * 1024 / 4 };
  ca.total4 = ca.seg[0].n4 + ca.seg[1].n4 + ca.seg[2].n4 + ca.seg[3].n4 + ca.seg[4].n4 + ca.seg[5].n4;
  cast_all<<<dim3(2048), 256, 0, stream>>>(ca);
  rope_table<<<dim3((SLEN * 16 + 255) / 256), 256, 0, stream>>>(cosT, sinT);

  // merged qa+kva projection (bf16 out)
  gemm_bf16k<<<dim3(64, 9), 256, 0, stream>>>(xb, wqkva_b, qakv_bf, SLEN, 1056, 1024);
  ln_both<<<dim3(8192), 256, 0, stream>>>(qakv_bf, qa_w, qa_b, kva_w, kva_b,
                                          qc_b, ckv_b, cosT, sinT, kpe_b);
  // wqb (rope+scale fused -> q_full) + wkvb in one launch
  gemm_dual<<<dim3(64, 20), 256, 0, stream>>>(qc_b, wqb_b, qf_b, ckv_b, wkvb_b, kvdec_bf,
                                              cosT, sinT);
  pack_kv2<<<dim3(64, 16), 256, 0, stream>>>(kvdec_bf, kpe_b, kf_b, vt_b);

  flash_part<<<dim3(NPAIR, 16), 256, 0, stream>>>(qf_b, kf_b, vt_b, Opart, MLpart);
  flash_combine<<<dim3(64, 16), 256, 0, stream>>>(Opart, MLpart, attn_b);
  gemm_f32k<<<dim3(64, 8), 256, 0, stream>>>(attn_b, wo_b, out, SLEN, 1024, 1024);

  (void)in_sizes; (void)n_in; (void)out_size; (void)ws_size;
}